// Round 10
// baseline (664.398 us; speedup 1.0000x reference)
//
#include <hip/hip_runtime.h>

#define SEQ 512
#define BATCH 128
#define DIM 1024
#define T 32

__device__ __forceinline__ float rlf(float x, int n) {
    return __int_as_float(__builtin_amdgcn_readlane(__float_as_int(x), n));
}

// wave-uniform mask bit: 512 bits in 8 u64 (SGPR-resident)
__device__ __forceinline__ int mbit(unsigned long long m0, unsigned long long m1,
        unsigned long long m2, unsigned long long m3, unsigned long long m4,
        unsigned long long m5, unsigned long long m6, unsigned long long m7, int i) {
    int w = i >> 6;
    unsigned long long cm =
        (w < 4) ? ((w < 2) ? (w == 0 ? m0 : m1) : (w == 2 ? m2 : m3))
                : ((w < 6) ? (w == 4 ? m4 : m5) : (w == 6 ? m6 : m7));
    return (int)((cm >> (i & 63)) & 1ULL);
}

#define BALLOTS(pre, bb) \
    unsigned long long pre##0 = __ballot(mask[(0 * 64 + tid) * BATCH + (bb)] != 0); \
    unsigned long long pre##1 = __ballot(mask[(1 * 64 + tid) * BATCH + (bb)] != 0); \
    unsigned long long pre##2 = __ballot(mask[(2 * 64 + tid) * BATCH + (bb)] != 0); \
    unsigned long long pre##3 = __ballot(mask[(3 * 64 + tid) * BATCH + (bb)] != 0); \
    unsigned long long pre##4 = __ballot(mask[(4 * 64 + tid) * BATCH + (bb)] != 0); \
    unsigned long long pre##5 = __ballot(mask[(5 * 64 + tid) * BATCH + (bb)] != 0); \
    unsigned long long pre##6 = __ballot(mask[(6 * 64 + tid) * BATCH + (bb)] != 0); \
    unsigned long long pre##7 = __ballot(mask[(7 * 64 + tid) * BATCH + (bb)] != 0);

#define MB(pre, i) mbit(pre##0, pre##1, pre##2, pre##3, pre##4, pre##5, pre##6, pre##7, (i))

#define MATVEC32(dst, src, Et) { \
    float q0 = 0.f, q1 = 0.f, q2 = 0.f, q3 = 0.f; \
    _Pragma("unroll") \
    for (int n = 0; n < 8; ++n) { \
        q0 = fmaf(rlf(src, 4 * n + 0), Et[4 * n + 0], q0); \
        q1 = fmaf(rlf(src, 4 * n + 1), Et[4 * n + 1], q1); \
        q2 = fmaf(rlf(src, 4 * n + 2), Et[4 * n + 2], q2); \
        q3 = fmaf(rlf(src, 4 * n + 3), Et[4 * n + 3], q3); \
    } \
    dst = (q0 + q1) + (q2 + q3); }

#define RLSUM32(dst, src) { \
    float s0 = 0.f, s1 = 0.f, s2 = 0.f, s3 = 0.f; \
    _Pragma("unroll") \
    for (int n = 0; n < 8; ++n) { \
        s0 += rlf(src, 4 * n + 0); \
        s1 += rlf(src, 4 * n + 1); \
        s2 += rlf(src, 4 * n + 2); \
        s3 += rlf(src, 4 * n + 3); \
    } \
    dst = (s0 + s1) + (s2 + s3); }

// stage 128 e-rows with exp applied (alpha/beta consume only exp(e))
#define STAGEXP(blk) do { \
    _Pragma("unroll") \
    for (int ps = 0; ps < 16; ++ps) { \
        int r = ps * 8 + r8; \
        float4 v = *(const float4*)&e[(size_t)(((blk) * 128 + r) * BATCH + b) * T + q * 4]; \
        v.x = __expf(v.x); v.y = __expf(v.y); v.z = __expf(v.z); v.w = __expf(v.w); \
        *(float4*)&ebuf[(blk) & 1][r * 32 + q * 4] = v; \
    } } while (0)

#define FLUSHPC(dstP, dstC, blk) do { \
    _Pragma("unroll") \
    for (int ps = 0; ps < 16; ++ps) { \
        int r = ps * 8 + r8; \
        float4 v = *(const float4*)&pbuf[(blk) & 1][r * 32 + q * 4]; \
        *(float4*)&dstP[(size_t)(((blk) * 128 + r) * BATCH + b) * T + q * 4] = v; \
    } \
    _Pragma("unroll") \
    for (int ps = 0; ps < 2; ++ps) { \
        int r = ps * 64 + tid; \
        dstC[(size_t)((blk) * 128 + r) * BATCH + b] = cbuf[(blk) & 1][r]; \
    } } while (0)

// viterbi: stage 64 raw e-rows for both chains
#define STAGEV(blk) do { \
    _Pragma("unroll") \
    for (int ps = 0; ps < 8; ++ps) { \
        int r = ps * 8 + r8; \
        float4 vA = *(const float4*)&e[(size_t)(((blk) * 64 + r) * BATCH + bA) * T + q * 4]; \
        float4 vB = *(const float4*)&e[(size_t)(((blk) * 64 + r) * BATCH + bB) * T + q * 4]; \
        *(float4*)&eA[(blk) & 1][r * 32 + q * 4] = vA; \
        *(float4*)&eB[(blk) & 1][r * 32 + q * 4] = vB; \
    } } while (0)

// exact (sc+trv)+ej candidates, pairwise first-wins max tree
#define VITSTEP(best, bi, sc, ej) { \
    float c_[32]; \
    _Pragma("unroll") \
    for (int n = 0; n < 32; ++n) c_[n] = (rlf(sc, n) + trv[n]) + (ej); \
    float w1[16]; int x1[16]; \
    _Pragma("unroll") \
    for (int n = 0; n < 16; ++n) { bool t = c_[2*n] >= c_[2*n+1]; w1[n] = t ? c_[2*n] : c_[2*n+1]; x1[n] = t ? 2*n : 2*n+1; } \
    float w2[8]; int x2[8]; \
    _Pragma("unroll") \
    for (int n = 0; n < 8; ++n) { bool t = w1[2*n] >= w1[2*n+1]; w2[n] = t ? w1[2*n] : w1[2*n+1]; x2[n] = t ? x1[2*n] : x1[2*n+1]; } \
    float w3[4]; int x3[4]; \
    _Pragma("unroll") \
    for (int n = 0; n < 4; ++n) { bool t = w2[2*n] >= w2[2*n+1]; w3[n] = t ? w2[2*n] : w2[2*n+1]; x3[n] = t ? x2[2*n] : x2[2*n+1]; } \
    float w4[2]; int x4[2]; \
    _Pragma("unroll") \
    for (int n = 0; n < 2; ++n) { bool t = w3[2*n] >= w3[2*n+1]; w4[n] = t ? w3[2*n] : w3[2*n+1]; x4[n] = t ? x3[2*n] : x3[2*n+1]; } \
    bool tt = w4[0] >= w4[1]; \
    best = tt ? w4[0] : w4[1]; \
    bi = tt ? x4[0] : x4[1]; }

// backtrace via readlane composition: 16 hist rows to regs, then uniform-index readlane chain
#define BACKTRACE(hist, tgbuf, fj_) { \
    int tag = __builtin_amdgcn_readfirstlane(fj_); \
    _Pragma("unroll 1") \
    for (int g = 31; g >= 0; --g) { \
        int h[16]; \
        _Pragma("unroll") \
        for (int k = 0; k < 16; ++k) h[k] = hist[(16 * g + k) * 32 + j]; \
        if (g == 31) h[15] = j;   /* identity map: composition no-op for i=511 */ \
        _Pragma("unroll") \
        for (int k = 15; k >= 0; --k) { \
            tag = __builtin_amdgcn_readlane(h[k], tag); \
            tgbuf[16 * g + k] = (unsigned char)tag; \
        } \
    } }

// ---------------- W transpose ----------------
__global__ void k_wt(const float* __restrict__ W, float* __restrict__ Wt)
{
    int idx = blockIdx.x * 256 + threadIdx.x;
    if (idx >= DIM * T) return;
    int d = idx >> 5, t = idx & 31;
    Wt[idx] = W[t * DIM + d];
}

// ---------------- emissions (unchanged) ----------------
__global__ __launch_bounds__(256) void k_emis(const float* __restrict__ A,
        const float* __restrict__ Wt, const float* __restrict__ bias,
        float* __restrict__ e)
{
    __shared__ float lds[64 * 37];
    int tid = threadIdx.x;
    int row0 = blockIdx.x * 64;
    int row = tid & 63;
    int grp = __builtin_amdgcn_readfirstlane(tid >> 6);
    int q = tid & 7;
    int rb = tid >> 3;

    float acc[8];
    #pragma unroll
    for (int t = 0; t < 8; ++t) acc[t] = bias[grp * 8 + t];

    const float* A0 = &A[(size_t)(row0 + rb) * DIM];
    const float* A1 = &A[(size_t)(row0 + rb + 32) * DIM];

    float4 v0 = *(const float4*)&A0[q * 4];
    float4 v1 = *(const float4*)&A1[q * 4];

    for (int ck = 0; ck < 32; ++ck) {
        lds[rb * 37 + q * 4 + 0] = v0.x;
        lds[rb * 37 + q * 4 + 1] = v0.y;
        lds[rb * 37 + q * 4 + 2] = v0.z;
        lds[rb * 37 + q * 4 + 3] = v0.w;
        lds[(rb + 32) * 37 + q * 4 + 0] = v1.x;
        lds[(rb + 32) * 37 + q * 4 + 1] = v1.y;
        lds[(rb + 32) * 37 + q * 4 + 2] = v1.z;
        lds[(rb + 32) * 37 + q * 4 + 3] = v1.w;
        __syncthreads();
        if (ck < 31) {
            v0 = *(const float4*)&A0[(ck + 1) * 32 + q * 4];
            v1 = *(const float4*)&A1[(ck + 1) * 32 + q * 4];
        }
        #pragma unroll
        for (int d = 0; d < 32; ++d) {
            float av = lds[row * 37 + d];
            const float* wrow = &Wt[(ck * 32 + d) * T + grp * 8];
            #pragma unroll
            for (int t = 0; t < 8; ++t)
                acc[t] = fmaf(av, wrow[t], acc[t]);
        }
        __syncthreads();
    }

    float4* eo = (float4*)&e[(size_t)(row0 + row) * T + grp * 8];
    float4 o0, o1;
    o0.x = acc[0]; o0.y = acc[1]; o0.z = acc[2]; o0.w = acc[3];
    o1.x = acc[4]; o1.y = acc[5]; o1.z = acc[6]; o1.w = acc[7];
    eo[0] = o0; eo[1] = o1;
}

// ---------------- recursions ----------------
// blocks 0..127 alpha, 128..255 beta (single chain, exp-staged e)
// blocks 256..319 viterbi DUAL-chain (2 batches/wave) + readlane backtrace
__global__ __launch_bounds__(64) void k_rec(const float* __restrict__ e,
        const int* __restrict__ mask,
        const float* __restrict__ trans,
        const float* __restrict__ start,
        const float* __restrict__ endp,
        float* __restrict__ pa, float* __restrict__ pb,
        double* __restrict__ Ca, double* __restrict__ Cb,
        double* __restrict__ zd,
        float* __restrict__ tags_out)
{
    __shared__ __align__(16) char smem[67584];
    int bid = blockIdx.x;
    int tid = threadIdx.x;
    int j   = tid & 31;
    int r8 = tid >> 3, q = tid & 7;

    if (bid < 256) {
        int role = bid >> 7;     // 0=alpha, 1=beta
        int b    = bid & 127;
        float (*ebuf)[4096] = (float(*)[4096])smem;              // exp(e), 2x128 rows
        float (*pbuf)[4096] = (float(*)[4096])(smem + 32768);
        double (*cbuf)[128] = (double(*)[128])(smem + 65536);

        BALLOTS(ma, b);
        float Et[32];

        if (role == 0) {
            #pragma unroll
            for (int n = 0; n < 32; ++n) Et[n] = __expf(trans[n * T + j]);

            STAGEXP(0);
            float a0 = e[(0 * BATCH + b) * T + j] + start[j];    // raw row 0 from global
            float m = a0;
            #pragma unroll
            for (int d = 1; d < 32; d <<= 1) m = fmaxf(m, __shfl_xor(m, d));
            float v = __expf(a0 - m);
            float s = v;
            #pragma unroll
            for (int d = 1; d < 32; d <<= 1) s += __shfl_xor(s, d);
            float p = v / s;
            double C = (double)m + (double)__logf(s);
            if (tid < 32) pbuf[0][j] = p;
            if (tid == 0) cbuf[0][0] = C;

            for (int c = 0; c < 4; ++c) {
                int i0 = c ? c * 128 : 1, i1 = c * 128 + 127;
                for (int i = i0; i <= i1; ++i) {
                    float ee = ebuf[c & 1][(i & 127) * 32 + j];   // exp(e_i), hidden under matvec
                    float q_;
                    MATVEC32(q_, p, Et);
                    float vv = q_ * ee;
                    if (MB(ma, i)) p = vv;
                    if (tid < 32) pbuf[c & 1][(i & 127) * 32 + j] = p;
                    if (tid == 0) cbuf[c & 1][i & 127] = C;
                    if ((i & 7) == 0) {
                        float ss; RLSUM32(ss, p);
                        p = p / ss; C += (double)__logf(ss);
                    }
                }
                if (c < 3) STAGEXP(c + 1);
                FLUSHPC(pa, Ca, c);
            }
            float sz0 = p * __expf(endp[j]);
            float sz; RLSUM32(sz, sz0);
            if (tid == 0) zd[b] = C + (double)__logf(sz);
        } else {
            #pragma unroll
            for (int n = 0; n < 32; ++n) Et[n] = __expf(trans[j * T + n]);

            STAGEXP(3);
            float v0 = endp[j];
            float m = v0;
            #pragma unroll
            for (int d = 1; d < 32; d <<= 1) m = fmaxf(m, __shfl_xor(m, d));
            float v = __expf(v0 - m);
            float s = v;
            #pragma unroll
            for (int d = 1; d < 32; d <<= 1) s += __shfl_xor(s, d);
            float p = v / s;
            double C = (double)m + (double)__logf(s);
            if (tid < 32) pbuf[1][127 * 32 + j] = p;
            if (tid == 0) cbuf[1][127] = C;

            float een = ebuf[1][127 * 32 + j];   // exp(e) row 511
            for (int c = 0; c < 4; ++c) {
                int iS = 511 - 128 * c;
                int iE = (c < 3) ? (384 - 128 * c) : 1;
                for (int i = iS; i >= iE; --i) {
                    float ee = een;
                    if (i > iE)
                        een = ebuf[((i - 1) >> 7) & 1][((i - 1) & 127) * 32 + j];
                    float pe = p * ee;
                    float q_;
                    MATVEC32(q_, pe, Et);
                    if (MB(ma, i)) p = q_;
                    int orow = i - 1, lb = (orow >> 7) & 1;
                    if (tid < 32) pbuf[lb][(orow & 127) * 32 + j] = p;
                    if (tid == 0) cbuf[lb][orow & 127] = C;
                    if ((i & 7) == 0) {
                        float ss; RLSUM32(ss, p);
                        p = p / ss; C += (double)__logf(ss);
                    }
                }
                if (c < 3) {
                    STAGEXP(2 - c);
                    een = ebuf[(2 - c) & 1][127 * 32 + j];
                }
                FLUSHPC(pb, Cb, 3 - c);
            }
        }
    } else {
        // ---- viterbi, 2 chains per wave ----
        int bA = (bid - 256) * 2, bB = bA + 1;
        float (*eA)[2048] = (float(*)[2048])smem;                 // raw e, 2x64 rows
        float (*eB)[2048] = (float(*)[2048])(smem + 16384);
        unsigned char* hA  = (unsigned char*)(smem + 32768);      // 16 KB hist each
        unsigned char* hB  = (unsigned char*)(smem + 49152);
        unsigned char* tgA = (unsigned char*)(smem + 65536);      // 512 B tags each
        unsigned char* tgB = tgA + 512;

        BALLOTS(ma, bA);
        BALLOTS(mb, bB);

        float trv[32];
        #pragma unroll
        for (int n = 0; n < 32; ++n) trv[n] = trans[n * T + j];

        STAGEV(0);
        float scA = start[j] + eA[0][j];
        float scB = start[j] + eB[0][j];

        for (int c = 0; c < 8; ++c) {
            int i0 = c ? c * 64 : 1, i1 = c * 64 + 63;
            for (int i = i0; i <= i1; ++i) {
                float ejA = eA[c & 1][(i & 63) * 32 + j];
                float ejB = eB[c & 1][(i & 63) * 32 + j];
                float bestA, bestB; int biA, biB;
                VITSTEP(bestA, biA, scA, ejA);
                VITSTEP(bestB, biB, scB, ejB);
                if (tid < 32) {
                    hA[(i - 1) * 32 + j] = (unsigned char)biA;
                    hB[(i - 1) * 32 + j] = (unsigned char)biB;
                }
                if (MB(ma, i)) scA = bestA;
                if (MB(mb, i)) scB = bestB;
            }
            if (c < 7) STAGEV(c + 1);
        }
        // final argmax (first index on ties), per chain
        float fsA = scA + endp[j]; int fjA = j;
        float fsB = scB + endp[j]; int fjB = j;
        #pragma unroll
        for (int d = 1; d < 32; d <<= 1) {
            float ovA = __shfl_xor(fsA, d); int ojA = __shfl_xor(fjA, d);
            if (ovA > fsA || (ovA == fsA && ojA < fjA)) { fsA = ovA; fjA = ojA; }
            float ovB = __shfl_xor(fsB, d); int ojB = __shfl_xor(fjB, d);
            if (ovB > fsB || (ovB == fsB && ojB < fjB)) { fsB = ovB; fjB = ojB; }
        }
        BACKTRACE(hA, tgA, fjA);
        BACKTRACE(hB, tgB, fjB);
        #pragma unroll
        for (int k2 = 0; k2 < 8; ++k2) {
            int idx = k2 * 64 + tid;
            tags_out[(size_t)idx * BATCH + bA] = (float)tgA[idx];
            tags_out[(size_t)idx * BATCH + bB] = (float)tgB[idx];
        }
    }
}

// ---------------- probs = pa * pb * exp(Ca + Cb - z) ----------------
__global__ __launch_bounds__(256) void k_probs(const float* __restrict__ pa,
        const float* __restrict__ pb, const double* __restrict__ Ca,
        const double* __restrict__ Cb, const double* __restrict__ zd,
        float* __restrict__ out)
{
    int idx = blockIdx.x * 256 + threadIdx.x;
    int ib = idx >> 3;
    int b = ib & (BATCH - 1);
    double ex = Ca[ib] + Cb[ib] - zd[b];
    double scl = exp(ex);
    float4 a = ((const float4*)pa)[idx];
    float4 c = ((const float4*)pb)[idx];
    float4 o;
    o.x = (float)((double)a.x * (double)c.x * scl);
    o.y = (float)((double)a.y * (double)c.y * scl);
    o.z = (float)((double)a.z * (double)c.z * scl);
    o.w = (float)((double)a.w * (double)c.w * scl);
    ((float4*)out)[idx] = o;
}

extern "C" void kernel_launch(void* const* d_in, const int* in_sizes, int n_in,
                              void* d_out, int out_size, void* d_ws, size_t ws_size,
                              hipStream_t stream) {
    const float* features = (const float*)d_in[0];
    const int*   mask     = (const int*)d_in[1];
    const float* W        = (const float*)d_in[2];
    const float* bias     = (const float*)d_in[3];
    const float* trans    = (const float*)d_in[4];
    const float* startp   = (const float*)d_in[5];
    const float* endp     = (const float*)d_in[6];

    char* ws = (char*)d_ws;
    double* Ca = (double*)(ws + 0);
    double* Cb = (double*)(ws + 524288);
    double* zd = (double*)(ws + 1048576);
    float*  Wt = (float*)(ws + 1049600);
    float*  e  = (float*)(ws + 1180672);
    float*  pa = (float*)(ws + 9569280);
    float*  pb = (float*)(ws + 17957888);

    float* probs_out = (float*)d_out;
    float* tags_out  = probs_out + (size_t)SEQ * BATCH * T;

    k_wt<<<128, 256, 0, stream>>>(W, Wt);
    k_emis<<<1024, 256, 0, stream>>>(features, Wt, bias, e);
    k_rec<<<320, 64, 0, stream>>>(e, mask, trans, startp, endp,
                                  pa, pb, Ca, Cb, zd, tags_out);
    k_probs<<<2048, 256, 0, stream>>>(pa, pb, Ca, Cb, zd, probs_out);
}

// Round 11
// 582.043 us; speedup vs baseline: 1.1415x; 1.1415x over previous
//
#include <hip/hip_runtime.h>

#define SEQ 512
#define BATCH 128
#define DIM 1024
#define T 32

__device__ __forceinline__ float rlf(float x, int n) {
    return __int_as_float(__builtin_amdgcn_readlane(__float_as_int(x), n));
}

// wave-uniform mask bit: 512 bits in 8 u64 (SGPR-resident)
__device__ __forceinline__ int mbit(unsigned long long m0, unsigned long long m1,
        unsigned long long m2, unsigned long long m3, unsigned long long m4,
        unsigned long long m5, unsigned long long m6, unsigned long long m7, int i) {
    int w = i >> 6;
    unsigned long long cm =
        (w < 4) ? ((w < 2) ? (w == 0 ? m0 : m1) : (w == 2 ? m2 : m3))
                : ((w < 6) ? (w == 4 ? m4 : m5) : (w == 6 ? m6 : m7));
    return (int)((cm >> (i & 63)) & 1ULL);
}

#define BALLOTS(pre, bb) \
    unsigned long long pre##0 = __ballot(mask[(0 * 64 + tid) * BATCH + (bb)] != 0); \
    unsigned long long pre##1 = __ballot(mask[(1 * 64 + tid) * BATCH + (bb)] != 0); \
    unsigned long long pre##2 = __ballot(mask[(2 * 64 + tid) * BATCH + (bb)] != 0); \
    unsigned long long pre##3 = __ballot(mask[(3 * 64 + tid) * BATCH + (bb)] != 0); \
    unsigned long long pre##4 = __ballot(mask[(4 * 64 + tid) * BATCH + (bb)] != 0); \
    unsigned long long pre##5 = __ballot(mask[(5 * 64 + tid) * BATCH + (bb)] != 0); \
    unsigned long long pre##6 = __ballot(mask[(6 * 64 + tid) * BATCH + (bb)] != 0); \
    unsigned long long pre##7 = __ballot(mask[(7 * 64 + tid) * BATCH + (bb)] != 0);

#define MB(pre, i) mbit(pre##0, pre##1, pre##2, pre##3, pre##4, pre##5, pre##6, pre##7, (i))

#define MATVEC32(dst, src, Et) { \
    float q0 = 0.f, q1 = 0.f, q2 = 0.f, q3 = 0.f; \
    _Pragma("unroll") \
    for (int n = 0; n < 8; ++n) { \
        q0 = fmaf(rlf(src, 4 * n + 0), Et[4 * n + 0], q0); \
        q1 = fmaf(rlf(src, 4 * n + 1), Et[4 * n + 1], q1); \
        q2 = fmaf(rlf(src, 4 * n + 2), Et[4 * n + 2], q2); \
        q3 = fmaf(rlf(src, 4 * n + 3), Et[4 * n + 3], q3); \
    } \
    dst = (q0 + q1) + (q2 + q3); }

#define RLSUM32(dst, src) { \
    float s0 = 0.f, s1 = 0.f, s2 = 0.f, s3 = 0.f; \
    _Pragma("unroll") \
    for (int n = 0; n < 8; ++n) { \
        s0 += rlf(src, 4 * n + 0); \
        s1 += rlf(src, 4 * n + 1); \
        s2 += rlf(src, 4 * n + 2); \
        s3 += rlf(src, 4 * n + 3); \
    } \
    dst = (s0 + s1) + (s2 + s3); }

// stage 128 e-rows with exp applied (alpha/beta consume only exp(e))
#define STAGEXP(blk) do { \
    _Pragma("unroll") \
    for (int ps = 0; ps < 16; ++ps) { \
        int r = ps * 8 + r8; \
        float4 v = *(const float4*)&e[(size_t)(((blk) * 128 + r) * BATCH + b) * T + q * 4]; \
        v.x = __expf(v.x); v.y = __expf(v.y); v.z = __expf(v.z); v.w = __expf(v.w); \
        *(float4*)&ebuf[(blk) & 1][r * 32 + q * 4] = v; \
    } } while (0)

#define FLUSHPC(dstP, dstC, blk) do { \
    _Pragma("unroll") \
    for (int ps = 0; ps < 16; ++ps) { \
        int r = ps * 8 + r8; \
        float4 v = *(const float4*)&pbuf[(blk) & 1][r * 32 + q * 4]; \
        *(float4*)&dstP[(size_t)(((blk) * 128 + r) * BATCH + b) * T + q * 4] = v; \
    } \
    _Pragma("unroll") \
    for (int ps = 0; ps < 2; ++ps) { \
        int r = ps * 64 + tid; \
        dstC[(size_t)((blk) * 128 + r) * BATCH + b] = cbuf[(blk) & 1][r]; \
    } } while (0)

// viterbi: stage 64 raw e-rows for both chains
#define STAGEV(blk) do { \
    _Pragma("unroll") \
    for (int ps = 0; ps < 8; ++ps) { \
        int r = ps * 8 + r8; \
        float4 vA = *(const float4*)&e[(size_t)(((blk) * 64 + r) * BATCH + bA) * T + q * 4]; \
        float4 vB = *(const float4*)&e[(size_t)(((blk) * 64 + r) * BATCH + bB) * T + q * 4]; \
        *(float4*)&eA[(blk) & 1][r * 32 + q * 4] = vA; \
        *(float4*)&eB[(blk) & 1][r * 32 + q * 4] = vB; \
    } } while (0)

// backtrace via readlane composition (verified round 10)
#define BACKTRACE(hist, tgbuf, fj_) { \
    int tag = __builtin_amdgcn_readfirstlane(fj_); \
    _Pragma("unroll 1") \
    for (int g = 31; g >= 0; --g) { \
        int h[16]; \
        _Pragma("unroll") \
        for (int k = 0; k < 16; ++k) h[k] = hist[(16 * g + k) * 32 + j]; \
        if (g == 31) h[15] = j;   /* identity: i=511 has no hist row */ \
        _Pragma("unroll") \
        for (int k = 15; k >= 0; --k) { \
            tag = __builtin_amdgcn_readlane(h[k], tag); \
            tgbuf[16 * g + k] = (unsigned char)tag; \
        } \
    } }

// ---------------- W transpose ----------------
__global__ void k_wt(const float* __restrict__ W, float* __restrict__ Wt)
{
    int idx = blockIdx.x * 256 + threadIdx.x;
    if (idx >= DIM * T) return;
    int d = idx >> 5, t = idx & 31;
    Wt[idx] = W[t * DIM + d];
}

// ---------------- emissions (unchanged, verified) ----------------
__global__ __launch_bounds__(256) void k_emis(const float* __restrict__ A,
        const float* __restrict__ Wt, const float* __restrict__ bias,
        float* __restrict__ e)
{
    __shared__ float lds[64 * 37];
    int tid = threadIdx.x;
    int row0 = blockIdx.x * 64;
    int row = tid & 63;
    int grp = __builtin_amdgcn_readfirstlane(tid >> 6);
    int q = tid & 7;
    int rb = tid >> 3;

    float acc[8];
    #pragma unroll
    for (int t = 0; t < 8; ++t) acc[t] = bias[grp * 8 + t];

    const float* A0 = &A[(size_t)(row0 + rb) * DIM];
    const float* A1 = &A[(size_t)(row0 + rb + 32) * DIM];

    float4 v0 = *(const float4*)&A0[q * 4];
    float4 v1 = *(const float4*)&A1[q * 4];

    for (int ck = 0; ck < 32; ++ck) {
        lds[rb * 37 + q * 4 + 0] = v0.x;
        lds[rb * 37 + q * 4 + 1] = v0.y;
        lds[rb * 37 + q * 4 + 2] = v0.z;
        lds[rb * 37 + q * 4 + 3] = v0.w;
        lds[(rb + 32) * 37 + q * 4 + 0] = v1.x;
        lds[(rb + 32) * 37 + q * 4 + 1] = v1.y;
        lds[(rb + 32) * 37 + q * 4 + 2] = v1.z;
        lds[(rb + 32) * 37 + q * 4 + 3] = v1.w;
        __syncthreads();
        if (ck < 31) {
            v0 = *(const float4*)&A0[(ck + 1) * 32 + q * 4];
            v1 = *(const float4*)&A1[(ck + 1) * 32 + q * 4];
        }
        #pragma unroll
        for (int d = 0; d < 32; ++d) {
            float av = lds[row * 37 + d];
            const float* wrow = &Wt[(ck * 32 + d) * T + grp * 8];
            #pragma unroll
            for (int t = 0; t < 8; ++t)
                acc[t] = fmaf(av, wrow[t], acc[t]);
        }
        __syncthreads();
    }

    float4* eo = (float4*)&e[(size_t)(row0 + row) * T + grp * 8];
    float4 o0, o1;
    o0.x = acc[0]; o0.y = acc[1]; o0.z = acc[2]; o0.w = acc[3];
    o1.x = acc[4]; o1.y = acc[5]; o1.z = acc[6]; o1.w = acc[7];
    eo[0] = o0; eo[1] = o1;
}

// ---------------- recursions ----------------
// blocks 0..127 alpha, 128..255 beta (verified round-10 code)
// blocks 256..319 viterbi dual-chain: interleaved sequential-scan argmax,
// low register pressure so the compiler interleaves the two chains (ILP
// fills dependent-issue bubbles; round-10's tree version serialized).
__global__ __launch_bounds__(64) void k_rec(const float* __restrict__ e,
        const int* __restrict__ mask,
        const float* __restrict__ trans,
        const float* __restrict__ start,
        const float* __restrict__ endp,
        float* __restrict__ pa, float* __restrict__ pb,
        double* __restrict__ Ca, double* __restrict__ Cb,
        double* __restrict__ zd,
        float* __restrict__ tags_out)
{
    __shared__ __align__(16) char smem[67584];
    int bid = blockIdx.x;
    int tid = threadIdx.x;
    int j   = tid & 31;
    int r8 = tid >> 3, q = tid & 7;

    if (bid < 256) {
        int role = bid >> 7;     // 0=alpha, 1=beta
        int b    = bid & 127;
        float (*ebuf)[4096] = (float(*)[4096])smem;
        float (*pbuf)[4096] = (float(*)[4096])(smem + 32768);
        double (*cbuf)[128] = (double(*)[128])(smem + 65536);

        BALLOTS(ma, b);
        float Et[32];

        if (role == 0) {
            #pragma unroll
            for (int n = 0; n < 32; ++n) Et[n] = __expf(trans[n * T + j]);

            STAGEXP(0);
            float a0 = e[(0 * BATCH + b) * T + j] + start[j];
            float m = a0;
            #pragma unroll
            for (int d = 1; d < 32; d <<= 1) m = fmaxf(m, __shfl_xor(m, d));
            float v = __expf(a0 - m);
            float s = v;
            #pragma unroll
            for (int d = 1; d < 32; d <<= 1) s += __shfl_xor(s, d);
            float p = v / s;
            double C = (double)m + (double)__logf(s);
            if (tid < 32) pbuf[0][j] = p;
            if (tid == 0) cbuf[0][0] = C;

            for (int c = 0; c < 4; ++c) {
                int i0 = c ? c * 128 : 1, i1 = c * 128 + 127;
                for (int i = i0; i <= i1; ++i) {
                    float ee = ebuf[c & 1][(i & 127) * 32 + j];
                    float q_;
                    MATVEC32(q_, p, Et);
                    float vv = q_ * ee;
                    if (MB(ma, i)) p = vv;
                    if (tid < 32) pbuf[c & 1][(i & 127) * 32 + j] = p;
                    if (tid == 0) cbuf[c & 1][i & 127] = C;
                    if ((i & 7) == 0) {
                        float ss; RLSUM32(ss, p);
                        p = p / ss; C += (double)__logf(ss);
                    }
                }
                if (c < 3) STAGEXP(c + 1);
                FLUSHPC(pa, Ca, c);
            }
            float sz0 = p * __expf(endp[j]);
            float sz; RLSUM32(sz, sz0);
            if (tid == 0) zd[b] = C + (double)__logf(sz);
        } else {
            #pragma unroll
            for (int n = 0; n < 32; ++n) Et[n] = __expf(trans[j * T + n]);

            STAGEXP(3);
            float v0 = endp[j];
            float m = v0;
            #pragma unroll
            for (int d = 1; d < 32; d <<= 1) m = fmaxf(m, __shfl_xor(m, d));
            float v = __expf(v0 - m);
            float s = v;
            #pragma unroll
            for (int d = 1; d < 32; d <<= 1) s += __shfl_xor(s, d);
            float p = v / s;
            double C = (double)m + (double)__logf(s);
            if (tid < 32) pbuf[1][127 * 32 + j] = p;
            if (tid == 0) cbuf[1][127] = C;

            float een = ebuf[1][127 * 32 + j];
            for (int c = 0; c < 4; ++c) {
                int iS = 511 - 128 * c;
                int iE = (c < 3) ? (384 - 128 * c) : 1;
                for (int i = iS; i >= iE; --i) {
                    float ee = een;
                    if (i > iE)
                        een = ebuf[((i - 1) >> 7) & 1][((i - 1) & 127) * 32 + j];
                    float pe = p * ee;
                    float q_;
                    MATVEC32(q_, pe, Et);
                    if (MB(ma, i)) p = q_;
                    int orow = i - 1, lb = (orow >> 7) & 1;
                    if (tid < 32) pbuf[lb][(orow & 127) * 32 + j] = p;
                    if (tid == 0) cbuf[lb][orow & 127] = C;
                    if ((i & 7) == 0) {
                        float ss; RLSUM32(ss, p);
                        p = p / ss; C += (double)__logf(ss);
                    }
                }
                if (c < 3) {
                    STAGEXP(2 - c);
                    een = ebuf[(2 - c) & 1][127 * 32 + j];
                }
                FLUSHPC(pb, Cb, 3 - c);
            }
        }
    } else {
        // ---- viterbi dual-chain, interleaved sequential-scan argmax ----
        int bA = (bid - 256) * 2, bB = bA + 1;
        float (*eA)[2048] = (float(*)[2048])smem;
        float (*eB)[2048] = (float(*)[2048])(smem + 16384);
        unsigned char* hA  = (unsigned char*)(smem + 32768);
        unsigned char* hB  = (unsigned char*)(smem + 49152);
        unsigned char* tgA = (unsigned char*)(smem + 65536);
        unsigned char* tgB = tgA + 512;

        BALLOTS(ma, bA);
        BALLOTS(mb, bB);

        float trv[32];
        #pragma unroll
        for (int n = 0; n < 32; ++n) trv[n] = trans[n * T + j];

        STAGEV(0);
        float scA = start[j] + eA[0][j];
        float scB = start[j] + eB[0][j];
        float ejA = eA[0][32 + j];   // row 1 prefetch
        float ejB = eB[0][32 + j];

        for (int c = 0; c < 8; ++c) {
            int i0 = c ? c * 64 : 1, i1 = c * 64 + 63;
            for (int i = i0; i <= i1; ++i) {
                float eja = ejA, ejb = ejB;
                if (i < i1) {   // in-chunk prefetch of row i+1
                    ejA = eA[c & 1][((i + 1) & 63) * 32 + j];
                    ejB = eB[c & 1][((i + 1) & 63) * 32 + j];
                }
                // interleaved running-max scans (strict > keeps first index:
                // identical result to the reference's first-wins argmax)
                float bsA, bsB; int biA, biB;
                {
                    float sA = rlf(scA, 0), sB = rlf(scB, 0);
                    bsA = (sA + trv[0]) + eja; biA = 0;
                    bsB = (sB + trv[0]) + ejb; biB = 0;
                }
                #pragma unroll
                for (int n = 1; n < 32; ++n) {
                    float sA = rlf(scA, n); float sB = rlf(scB, n);
                    float cA = (sA + trv[n]) + eja;
                    float cB = (sB + trv[n]) + ejb;
                    bool tA = cA > bsA; bool tB = cB > bsB;
                    bsA = tA ? cA : bsA; biA = tA ? n : biA;
                    bsB = tB ? cB : bsB; biB = tB ? n : biB;
                }
                // both halves computed identically -> same-value write race is benign
                hA[(i - 1) * 32 + j] = (unsigned char)biA;
                hB[(i - 1) * 32 + j] = (unsigned char)biB;
                if (MB(ma, i)) scA = bsA;
                if (MB(mb, i)) scB = bsB;
            }
            if (c < 7) {
                STAGEV(c + 1);
                ejA = eA[(c + 1) & 1][j];   // row 64(c+1), local row 0
                ejB = eB[(c + 1) & 1][j];
            }
        }
        // final argmax (first index on ties), per chain
        float fsA = scA + endp[j]; int fjA = j;
        float fsB = scB + endp[j]; int fjB = j;
        #pragma unroll
        for (int d = 1; d < 32; d <<= 1) {
            float ovA = __shfl_xor(fsA, d); int ojA = __shfl_xor(fjA, d);
            if (ovA > fsA || (ovA == fsA && ojA < fjA)) { fsA = ovA; fjA = ojA; }
            float ovB = __shfl_xor(fsB, d); int ojB = __shfl_xor(fjB, d);
            if (ovB > fsB || (ovB == fsB && ojB < fjB)) { fsB = ovB; fjB = ojB; }
        }
        BACKTRACE(hA, tgA, fjA);
        BACKTRACE(hB, tgB, fjB);
        #pragma unroll
        for (int k2 = 0; k2 < 8; ++k2) {
            int idx = k2 * 64 + tid;
            tags_out[(size_t)idx * BATCH + bA] = (float)tgA[idx];
            tags_out[(size_t)idx * BATCH + bB] = (float)tgB[idx];
        }
    }
}

// ---------------- probs = pa * pb * exp(Ca + Cb - z) ----------------
__global__ __launch_bounds__(256) void k_probs(const float* __restrict__ pa,
        const float* __restrict__ pb, const double* __restrict__ Ca,
        const double* __restrict__ Cb, const double* __restrict__ zd,
        float* __restrict__ out)
{
    int idx = blockIdx.x * 256 + threadIdx.x;
    int ib = idx >> 3;
    int b = ib & (BATCH - 1);
    double ex = Ca[ib] + Cb[ib] - zd[b];
    double scl = exp(ex);
    float4 a = ((const float4*)pa)[idx];
    float4 c = ((const float4*)pb)[idx];
    float4 o;
    o.x = (float)((double)a.x * (double)c.x * scl);
    o.y = (float)((double)a.y * (double)c.y * scl);
    o.z = (float)((double)a.z * (double)c.z * scl);
    o.w = (float)((double)a.w * (double)c.w * scl);
    ((float4*)out)[idx] = o;
}

extern "C" void kernel_launch(void* const* d_in, const int* in_sizes, int n_in,
                              void* d_out, int out_size, void* d_ws, size_t ws_size,
                              hipStream_t stream) {
    const float* features = (const float*)d_in[0];
    const int*   mask     = (const int*)d_in[1];
    const float* W        = (const float*)d_in[2];
    const float* bias     = (const float*)d_in[3];
    const float* trans    = (const float*)d_in[4];
    const float* startp   = (const float*)d_in[5];
    const float* endp     = (const float*)d_in[6];

    char* ws = (char*)d_ws;
    double* Ca = (double*)(ws + 0);
    double* Cb = (double*)(ws + 524288);
    double* zd = (double*)(ws + 1048576);
    float*  Wt = (float*)(ws + 1049600);
    float*  e  = (float*)(ws + 1180672);
    float*  pa = (float*)(ws + 9569280);
    float*  pb = (float*)(ws + 17957888);

    float* probs_out = (float*)d_out;
    float* tags_out  = probs_out + (size_t)SEQ * BATCH * T;

    k_wt<<<128, 256, 0, stream>>>(W, Wt);
    k_emis<<<1024, 256, 0, stream>>>(features, Wt, bias, e);
    k_rec<<<320, 64, 0, stream>>>(e, mask, trans, startp, endp,
                                  pa, pb, Ca, Cb, zd, tags_out);
    k_probs<<<2048, 256, 0, stream>>>(pa, pb, Ca, Cb, zd, probs_out);
}

// Round 13
// 329.987 us; speedup vs baseline: 2.0134x; 1.7638x over previous
//
#include <hip/hip_runtime.h>

#define SEQ 512
#define BATCH 128
#define DIM 1024
#define T 32

__device__ __forceinline__ float rlf(float x, int n) {
    return __int_as_float(__builtin_amdgcn_readlane(__float_as_int(x), n));
}

// wave-uniform mask bit: 512 bits in 8 u64 (SGPR-resident)
__device__ __forceinline__ int mbit(unsigned long long m0, unsigned long long m1,
        unsigned long long m2, unsigned long long m3, unsigned long long m4,
        unsigned long long m5, unsigned long long m6, unsigned long long m7, int i) {
    int w = i >> 6;
    unsigned long long cm =
        (w < 4) ? ((w < 2) ? (w == 0 ? m0 : m1) : (w == 2 ? m2 : m3))
                : ((w < 6) ? (w == 4 ? m4 : m5) : (w == 6 ? m6 : m7));
    return (int)((cm >> (i & 63)) & 1ULL);
}

#define BALLOTS(pre, bb) \
    unsigned long long pre##0 = __ballot(mask[(0 * 64 + tid) * BATCH + (bb)] != 0); \
    unsigned long long pre##1 = __ballot(mask[(1 * 64 + tid) * BATCH + (bb)] != 0); \
    unsigned long long pre##2 = __ballot(mask[(2 * 64 + tid) * BATCH + (bb)] != 0); \
    unsigned long long pre##3 = __ballot(mask[(3 * 64 + tid) * BATCH + (bb)] != 0); \
    unsigned long long pre##4 = __ballot(mask[(4 * 64 + tid) * BATCH + (bb)] != 0); \
    unsigned long long pre##5 = __ballot(mask[(5 * 64 + tid) * BATCH + (bb)] != 0); \
    unsigned long long pre##6 = __ballot(mask[(6 * 64 + tid) * BATCH + (bb)] != 0); \
    unsigned long long pre##7 = __ballot(mask[(7 * 64 + tid) * BATCH + (bb)] != 0);

#define MB(pre, i) mbit(pre##0, pre##1, pre##2, pre##3, pre##4, pre##5, pre##6, pre##7, (i))

#define MATVEC32(dst, src, Et) { \
    float q0 = 0.f, q1 = 0.f, q2 = 0.f, q3 = 0.f; \
    _Pragma("unroll") \
    for (int n = 0; n < 8; ++n) { \
        q0 = fmaf(rlf(src, 4 * n + 0), Et[4 * n + 0], q0); \
        q1 = fmaf(rlf(src, 4 * n + 1), Et[4 * n + 1], q1); \
        q2 = fmaf(rlf(src, 4 * n + 2), Et[4 * n + 2], q2); \
        q3 = fmaf(rlf(src, 4 * n + 3), Et[4 * n + 3], q3); \
    } \
    dst = (q0 + q1) + (q2 + q3); }

#define RLSUM32(dst, src) { \
    float s0 = 0.f, s1 = 0.f, s2 = 0.f, s3 = 0.f; \
    _Pragma("unroll") \
    for (int n = 0; n < 8; ++n) { \
        s0 += rlf(src, 4 * n + 0); \
        s1 += rlf(src, 4 * n + 1); \
        s2 += rlf(src, 4 * n + 2); \
        s3 += rlf(src, 4 * n + 3); \
    } \
    dst = (s0 + s1) + (s2 + s3); }

// alpha/beta: stage 128 e-rows with exp applied
#define STAGEXP(blk) do { \
    _Pragma("unroll") \
    for (int ps = 0; ps < 16; ++ps) { \
        int r = ps * 8 + r8; \
        float4 v = *(const float4*)&e[(size_t)(((blk) * 128 + r) * BATCH + b) * T + q * 4]; \
        v.x = __expf(v.x); v.y = __expf(v.y); v.z = __expf(v.z); v.w = __expf(v.w); \
        *(float4*)&ebuf[(blk) & 1][r * 32 + q * 4] = v; \
    } } while (0)

#define FLUSHPC(dstP, dstC, blk) do { \
    _Pragma("unroll") \
    for (int ps = 0; ps < 16; ++ps) { \
        int r = ps * 8 + r8; \
        float4 v = *(const float4*)&pbuf[(blk) & 1][r * 32 + q * 4]; \
        *(float4*)&dstP[(size_t)(((blk) * 128 + r) * BATCH + b) * T + q * 4] = v; \
    } \
    _Pragma("unroll") \
    for (int ps = 0; ps < 2; ++ps) { \
        int r = ps * 64 + tid; \
        dstC[(size_t)((blk) * 128 + r) * BATCH + b] = cbuf[(blk) & 1][r]; \
    } } while (0)

// viterbi: stage 64 raw e-rows (single buffer)
#define STAGEV(blk) do { \
    _Pragma("unroll") \
    for (int ps = 0; ps < 8; ++ps) { \
        int r = ps * 8 + r8; \
        float4 v = *(const float4*)&e[(size_t)(((blk) * 64 + r) * BATCH + b2) * T + q * 4]; \
        *(float4*)&ebufv[r * 32 + q * 4] = v; \
    } } while (0)

// ---------------- W transpose ----------------
__global__ void k_wt(const float* __restrict__ W, float* __restrict__ Wt)
{
    int idx = blockIdx.x * 256 + threadIdx.x;
    if (idx >= DIM * T) return;
    int d = idx >> 5, t = idx & 31;
    Wt[idx] = W[t * DIM + d];
}

// ---------------- emissions (unchanged, verified) ----------------
__global__ __launch_bounds__(256) void k_emis(const float* __restrict__ A,
        const float* __restrict__ Wt, const float* __restrict__ bias,
        float* __restrict__ e)
{
    __shared__ float lds[64 * 37];
    int tid = threadIdx.x;
    int row0 = blockIdx.x * 64;
    int row = tid & 63;
    int grp = __builtin_amdgcn_readfirstlane(tid >> 6);
    int q = tid & 7;
    int rb = tid >> 3;

    float acc[8];
    #pragma unroll
    for (int t = 0; t < 8; ++t) acc[t] = bias[grp * 8 + t];

    const float* A0 = &A[(size_t)(row0 + rb) * DIM];
    const float* A1 = &A[(size_t)(row0 + rb + 32) * DIM];

    float4 v0 = *(const float4*)&A0[q * 4];
    float4 v1 = *(const float4*)&A1[q * 4];

    for (int ck = 0; ck < 32; ++ck) {
        lds[rb * 37 + q * 4 + 0] = v0.x;
        lds[rb * 37 + q * 4 + 1] = v0.y;
        lds[rb * 37 + q * 4 + 2] = v0.z;
        lds[rb * 37 + q * 4 + 3] = v0.w;
        lds[(rb + 32) * 37 + q * 4 + 0] = v1.x;
        lds[(rb + 32) * 37 + q * 4 + 1] = v1.y;
        lds[(rb + 32) * 37 + q * 4 + 2] = v1.z;
        lds[(rb + 32) * 37 + q * 4 + 3] = v1.w;
        __syncthreads();
        if (ck < 31) {
            v0 = *(const float4*)&A0[(ck + 1) * 32 + q * 4];
            v1 = *(const float4*)&A1[(ck + 1) * 32 + q * 4];
        }
        #pragma unroll
        for (int d = 0; d < 32; ++d) {
            float av = lds[row * 37 + d];
            const float* wrow = &Wt[(ck * 32 + d) * T + grp * 8];
            #pragma unroll
            for (int t = 0; t < 8; ++t)
                acc[t] = fmaf(av, wrow[t], acc[t]);
        }
        __syncthreads();
    }

    float4* eo = (float4*)&e[(size_t)(row0 + row) * T + grp * 8];
    float4 o0, o1;
    o0.x = acc[0]; o0.y = acc[1]; o0.z = acc[2]; o0.w = acc[3];
    o1.x = acc[4]; o1.y = acc[5]; o1.z = acc[6]; o1.w = acc[7];
    eo[0] = o0; eo[1] = o1;
}

// ---------------- recursions ----------------
// blocks 0..127 alpha, 128..255 beta (verified round-11 code, unchanged)
// blocks 256..383 viterbi: value-only forward (no argmax tracking; score rows
// stored to LDS) + ballot-equality backtrace (recompute reference candidates
// exactly, find first n with c_n == v). Bit-exact: fl(max fl(s+t) + e) ==
// max fl(fl(s+t)+e) by rounding monotonicity; max itself never rounds.
__global__ __launch_bounds__(64) void k_rec(const float* __restrict__ e,
        const int* __restrict__ mask,
        const float* __restrict__ trans,
        const float* __restrict__ start,
        const float* __restrict__ endp,
        float* __restrict__ pa, float* __restrict__ pb,
        double* __restrict__ Ca, double* __restrict__ Cb,
        double* __restrict__ zd,
        float* __restrict__ tags_out)
{
    __shared__ __align__(16) char smem[78336];
    int bid = blockIdx.x;
    int tid = threadIdx.x;
    int j   = tid & 31;
    int r8 = tid >> 3, q = tid & 7;

    if (bid < 256) {
        int role = bid >> 7;     // 0=alpha, 1=beta
        int b    = bid & 127;
        float (*ebuf)[4096] = (float(*)[4096])smem;
        float (*pbuf)[4096] = (float(*)[4096])(smem + 32768);
        double (*cbuf)[128] = (double(*)[128])(smem + 65536);

        BALLOTS(ma, b);
        float Et[32];

        if (role == 0) {
            #pragma unroll
            for (int n = 0; n < 32; ++n) Et[n] = __expf(trans[n * T + j]);

            STAGEXP(0);
            float a0 = e[(0 * BATCH + b) * T + j] + start[j];
            float m = a0;
            #pragma unroll
            for (int d = 1; d < 32; d <<= 1) m = fmaxf(m, __shfl_xor(m, d));
            float v = __expf(a0 - m);
            float s = v;
            #pragma unroll
            for (int d = 1; d < 32; d <<= 1) s += __shfl_xor(s, d);
            float p = v / s;
            double C = (double)m + (double)__logf(s);
            if (tid < 32) pbuf[0][j] = p;
            if (tid == 0) cbuf[0][0] = C;

            for (int c = 0; c < 4; ++c) {
                int i0 = c ? c * 128 : 1, i1 = c * 128 + 127;
                for (int i = i0; i <= i1; ++i) {
                    float ee = ebuf[c & 1][(i & 127) * 32 + j];
                    float q_;
                    MATVEC32(q_, p, Et);
                    float vv = q_ * ee;
                    if (MB(ma, i)) p = vv;
                    if (tid < 32) pbuf[c & 1][(i & 127) * 32 + j] = p;
                    if (tid == 0) cbuf[c & 1][i & 127] = C;
                    if ((i & 7) == 0) {
                        float ss; RLSUM32(ss, p);
                        p = p / ss; C += (double)__logf(ss);
                    }
                }
                if (c < 3) STAGEXP(c + 1);
                FLUSHPC(pa, Ca, c);
            }
            float sz0 = p * __expf(endp[j]);
            float sz; RLSUM32(sz, sz0);
            if (tid == 0) zd[b] = C + (double)__logf(sz);
        } else {
            #pragma unroll
            for (int n = 0; n < 32; ++n) Et[n] = __expf(trans[j * T + n]);

            STAGEXP(3);
            float v0 = endp[j];
            float m = v0;
            #pragma unroll
            for (int d = 1; d < 32; d <<= 1) m = fmaxf(m, __shfl_xor(m, d));
            float v = __expf(v0 - m);
            float s = v;
            #pragma unroll
            for (int d = 1; d < 32; d <<= 1) s += __shfl_xor(s, d);
            float p = v / s;
            double C = (double)m + (double)__logf(s);
            if (tid < 32) pbuf[1][127 * 32 + j] = p;
            if (tid == 0) cbuf[1][127] = C;

            float een = ebuf[1][127 * 32 + j];
            for (int c = 0; c < 4; ++c) {
                int iS = 511 - 128 * c;
                int iE = (c < 3) ? (384 - 128 * c) : 1;
                for (int i = iS; i >= iE; --i) {
                    float ee = een;
                    if (i > iE)
                        een = ebuf[((i - 1) >> 7) & 1][((i - 1) & 127) * 32 + j];
                    float pe = p * ee;
                    float q_;
                    MATVEC32(q_, pe, Et);
                    if (MB(ma, i)) p = q_;
                    int orow = i - 1, lb = (orow >> 7) & 1;
                    if (tid < 32) pbuf[lb][(orow & 127) * 32 + j] = p;
                    if (tid == 0) cbuf[lb][orow & 127] = C;
                    if ((i & 7) == 0) {
                        float ss; RLSUM32(ss, p);
                        p = p / ss; C += (double)__logf(ss);
                    }
                }
                if (c < 3) {
                    STAGEXP(2 - c);
                    een = ebuf[(2 - c) & 1][127 * 32 + j];
                }
                FLUSHPC(pb, Cb, 3 - c);
            }
        }
    } else {
        // ---- viterbi: value-only forward + ballot-equality backtrace ----
        int b2 = bid - 256;
        float* ebufv = (float*)smem;                       //  8 KB: 64 rows x 32
        float* sbuf  = (float*)(smem + 8192);              // 64 KB: 512 rows x 32
        float* tlds  = (float*)(smem + 73728);             //  4 KB: trans copy
        unsigned char* tagb = (unsigned char*)(smem + 77824);  // 512 B

        BALLOTS(ma, b2);

        // trans copy to LDS (backtrace reads rows by lane)
        #pragma unroll
        for (int k = 0; k < 16; ++k)
            tlds[k * 64 + tid] = trans[k * 64 + tid];

        float trv[32];
        #pragma unroll
        for (int n = 0; n < 32; ++n) trv[n] = trans[n * T + j];

        STAGEV(0);
        float sc = start[j] + ebufv[j];
        sbuf[j] = sc;                      // row 0 (dup halves: benign)

        // ---- forward: 8 chunks x 64 steps ----
        for (int c = 0; c < 8; ++c) {
            int i0 = c ? c * 64 : 1, i1 = c * 64 + 63;
            for (int i = i0; i <= i1; ++i) {
                float ej = ebufv[(i & 63) * 32 + j];
                float cc[32];
                #pragma unroll
                for (int n = 0; n < 32; ++n)
                    cc[n] = rlf(sc, n) + trv[n];
                // value-only max tree (max is exact; any shape OK)
                float w1[16];
                #pragma unroll
                for (int n = 0; n < 16; ++n) w1[n] = fmaxf(cc[2*n], cc[2*n+1]);
                float w2[8];
                #pragma unroll
                for (int n = 0; n < 8; ++n) w2[n] = fmaxf(w1[2*n], w1[2*n+1]);
                float w3[4];
                #pragma unroll
                for (int n = 0; n < 4; ++n) w3[n] = fmaxf(w2[2*n], w2[2*n+1]);
                float m_ = fmaxf(fmaxf(w3[0], w3[1]), fmaxf(w3[2], w3[3]));
                float v = m_ + ej;
                if (MB(ma, i)) sc = v;
                sbuf[i * 32 + j] = sc;      // post-mask score row
            }
            if (c < 7) STAGEV(c + 1);
        }

        // final argmax over j (first index on ties)
        float fs = sc + endp[j];
        int fj = j;
        #pragma unroll
        for (int d = 1; d < 32; d <<= 1) {
            float ov = __shfl_xor(fs, d); int oj = __shfl_xor(fj, d);
            if (ov > fs || (ov == fs && oj < fj)) { fs = ov; fj = oj; }
        }
        int jstar = __builtin_amdgcn_readfirstlane(fj);
        tagb[SEQ - 1] = (unsigned char)jstar;

        // ---- backtrace: lane n recomputes reference candidate c_n exactly ----
        int n = tid & 31;
        for (int c = 7; c >= 0; --c) {
            if (c < 7) STAGEV(c);           // ebufv <- chunk c (chunk 7 resident)
            int iS = c * 64 + 63, iE = c ? c * 64 : 1;
            for (int i = iS; i >= iE; --i) {
                float sn = sbuf[(i - 1) * 32 + n];
                float tn = tlds[n * 32 + jstar];
                float en = ebufv[(i & 63) * 32 + jstar];
                float cn = (sn + tn) + en;   // reference add order
                float v;
                if (MB(ma, i)) {
                    v = sbuf[i * 32 + jstar];   // == max_n cn (mask=1)
                } else {
                    v = cn;                      // exact fallback: wave max
                    #pragma unroll
                    for (int d = 1; d < 32; d <<= 1)
                        v = fmaxf(v, __shfl_xor(v, d));
                }
                unsigned long long bm = __ballot(cn == v);
                jstar = (int)__builtin_ctzll(bm);   // first n (lanes 32-63 mirror)
                tagb[i - 1] = (unsigned char)jstar;
            }
        }
        #pragma unroll
        for (int k2 = 0; k2 < 8; ++k2) {
            int idx = k2 * 64 + tid;
            tags_out[(size_t)idx * BATCH + b2] = (float)tagb[idx];
        }
    }
}

// ---------------- probs = pa * pb * exp(Ca + Cb - z) ----------------
__global__ __launch_bounds__(256) void k_probs(const float* __restrict__ pa,
        const float* __restrict__ pb, const double* __restrict__ Ca,
        const double* __restrict__ Cb, const double* __restrict__ zd,
        float* __restrict__ out)
{
    int idx = blockIdx.x * 256 + threadIdx.x;
    int ib = idx >> 3;
    int b = ib & (BATCH - 1);
    double ex = Ca[ib] + Cb[ib] - zd[b];
    double scl = exp(ex);
    float4 a = ((const float4*)pa)[idx];
    float4 c = ((const float4*)pb)[idx];
    float4 o;
    o.x = (float)((double)a.x * (double)c.x * scl);
    o.y = (float)((double)a.y * (double)c.y * scl);
    o.z = (float)((double)a.z * (double)c.z * scl);
    o.w = (float)((double)a.w * (double)c.w * scl);
    ((float4*)out)[idx] = o;
}

extern "C" void kernel_launch(void* const* d_in, const int* in_sizes, int n_in,
                              void* d_out, int out_size, void* d_ws, size_t ws_size,
                              hipStream_t stream) {
    const float* features = (const float*)d_in[0];
    const int*   mask     = (const int*)d_in[1];
    const float* W        = (const float*)d_in[2];
    const float* bias     = (const float*)d_in[3];
    const float* trans    = (const float*)d_in[4];
    const float* startp   = (const float*)d_in[5];
    const float* endp     = (const float*)d_in[6];

    char* ws = (char*)d_ws;
    double* Ca = (double*)(ws + 0);
    double* Cb = (double*)(ws + 524288);
    double* zd = (double*)(ws + 1048576);
    float*  Wt = (float*)(ws + 1049600);
    float*  e  = (float*)(ws + 1180672);
    float*  pa = (float*)(ws + 9569280);
    float*  pb = (float*)(ws + 17957888);

    float* probs_out = (float*)d_out;
    float* tags_out  = probs_out + (size_t)SEQ * BATCH * T;

    k_wt<<<128, 256, 0, stream>>>(W, Wt);
    k_emis<<<1024, 256, 0, stream>>>(features, Wt, bias, e);
    k_rec<<<384, 64, 0, stream>>>(e, mask, trans, startp, endp,
                                  pa, pb, Ca, Cb, zd, tags_out);
    k_probs<<<2048, 256, 0, stream>>>(pa, pb, Ca, Cb, zd, probs_out);
}

// Round 14
// 314.332 us; speedup vs baseline: 2.1137x; 1.0498x over previous
//
#include <hip/hip_runtime.h>

#define SEQ 512
#define BATCH 128
#define DIM 1024
#define T 32

__device__ __forceinline__ float rlf(float x, int n) {
    return __int_as_float(__builtin_amdgcn_readlane(__float_as_int(x), n));
}

// wave-uniform mask bit: 512 bits in 8 u64 (SGPR-resident)
__device__ __forceinline__ int mbit(unsigned long long m0, unsigned long long m1,
        unsigned long long m2, unsigned long long m3, unsigned long long m4,
        unsigned long long m5, unsigned long long m6, unsigned long long m7, int i) {
    int w = i >> 6;
    unsigned long long cm =
        (w < 4) ? ((w < 2) ? (w == 0 ? m0 : m1) : (w == 2 ? m2 : m3))
                : ((w < 6) ? (w == 4 ? m4 : m5) : (w == 6 ? m6 : m7));
    return (int)((cm >> (i & 63)) & 1ULL);
}

#define BALLOTS(pre, bb) \
    unsigned long long pre##0 = __ballot(mask[(0 * 64 + tid) * BATCH + (bb)] != 0); \
    unsigned long long pre##1 = __ballot(mask[(1 * 64 + tid) * BATCH + (bb)] != 0); \
    unsigned long long pre##2 = __ballot(mask[(2 * 64 + tid) * BATCH + (bb)] != 0); \
    unsigned long long pre##3 = __ballot(mask[(3 * 64 + tid) * BATCH + (bb)] != 0); \
    unsigned long long pre##4 = __ballot(mask[(4 * 64 + tid) * BATCH + (bb)] != 0); \
    unsigned long long pre##5 = __ballot(mask[(5 * 64 + tid) * BATCH + (bb)] != 0); \
    unsigned long long pre##6 = __ballot(mask[(6 * 64 + tid) * BATCH + (bb)] != 0); \
    unsigned long long pre##7 = __ballot(mask[(7 * 64 + tid) * BATCH + (bb)] != 0);

#define MB(pre, i) mbit(pre##0, pre##1, pre##2, pre##3, pre##4, pre##5, pre##6, pre##7, (i))

#define MATVEC32(dst, src, Et) { \
    float q0 = 0.f, q1 = 0.f, q2 = 0.f, q3 = 0.f; \
    _Pragma("unroll") \
    for (int n = 0; n < 8; ++n) { \
        q0 = fmaf(rlf(src, 4 * n + 0), Et[4 * n + 0], q0); \
        q1 = fmaf(rlf(src, 4 * n + 1), Et[4 * n + 1], q1); \
        q2 = fmaf(rlf(src, 4 * n + 2), Et[4 * n + 2], q2); \
        q3 = fmaf(rlf(src, 4 * n + 3), Et[4 * n + 3], q3); \
    } \
    dst = (q0 + q1) + (q2 + q3); }

#define RLSUM32(dst, src) { \
    float s0 = 0.f, s1 = 0.f, s2 = 0.f, s3 = 0.f; \
    _Pragma("unroll") \
    for (int n = 0; n < 8; ++n) { \
        s0 += rlf(src, 4 * n + 0); \
        s1 += rlf(src, 4 * n + 1); \
        s2 += rlf(src, 4 * n + 2); \
        s3 += rlf(src, 4 * n + 3); \
    } \
    dst = (s0 + s1) + (s2 + s3); }

// alpha/beta: stage 128 e-rows with exp applied
#define STAGEXP(blk) do { \
    _Pragma("unroll") \
    for (int ps = 0; ps < 16; ++ps) { \
        int r = ps * 8 + r8; \
        float4 v = *(const float4*)&e[(size_t)(((blk) * 128 + r) * BATCH + b) * T + q * 4]; \
        v.x = __expf(v.x); v.y = __expf(v.y); v.z = __expf(v.z); v.w = __expf(v.w); \
        *(float4*)&ebuf[(blk) & 1][r * 32 + q * 4] = v; \
    } } while (0)

#define FLUSHPC(dstP, dstC, blk) do { \
    _Pragma("unroll") \
    for (int ps = 0; ps < 16; ++ps) { \
        int r = ps * 8 + r8; \
        float4 v = *(const float4*)&pbuf[(blk) & 1][r * 32 + q * 4]; \
        *(float4*)&dstP[(size_t)(((blk) * 128 + r) * BATCH + b) * T + q * 4] = v; \
    } \
    _Pragma("unroll") \
    for (int ps = 0; ps < 2; ++ps) { \
        int r = ps * 64 + tid; \
        dstC[(size_t)((blk) * 128 + r) * BATCH + b] = cbuf[(blk) & 1][r]; \
    } } while (0)

// viterbi: stage 64 raw e-rows (single buffer)
#define STAGEV(blk) do { \
    _Pragma("unroll") \
    for (int ps = 0; ps < 8; ++ps) { \
        int r = ps * 8 + r8; \
        float4 v = *(const float4*)&e[(size_t)(((blk) * 64 + r) * BATCH + b2) * T + q * 4]; \
        *(float4*)&ebufv[r * 32 + q * 4] = v; \
    } } while (0)

// ---------------- W transpose ----------------
__global__ void k_wt(const float* __restrict__ W, float* __restrict__ Wt)
{
    int idx = blockIdx.x * 256 + threadIdx.x;
    if (idx >= DIM * T) return;
    int d = idx >> 5, t = idx & 31;
    Wt[idx] = W[t * DIM + d];
}

// ---------------- emissions (unchanged, verified) ----------------
__global__ __launch_bounds__(256) void k_emis(const float* __restrict__ A,
        const float* __restrict__ Wt, const float* __restrict__ bias,
        float* __restrict__ e)
{
    __shared__ float lds[64 * 37];
    int tid = threadIdx.x;
    int row0 = blockIdx.x * 64;
    int row = tid & 63;
    int grp = __builtin_amdgcn_readfirstlane(tid >> 6);
    int q = tid & 7;
    int rb = tid >> 3;

    float acc[8];
    #pragma unroll
    for (int t = 0; t < 8; ++t) acc[t] = bias[grp * 8 + t];

    const float* A0 = &A[(size_t)(row0 + rb) * DIM];
    const float* A1 = &A[(size_t)(row0 + rb + 32) * DIM];

    float4 v0 = *(const float4*)&A0[q * 4];
    float4 v1 = *(const float4*)&A1[q * 4];

    for (int ck = 0; ck < 32; ++ck) {
        lds[rb * 37 + q * 4 + 0] = v0.x;
        lds[rb * 37 + q * 4 + 1] = v0.y;
        lds[rb * 37 + q * 4 + 2] = v0.z;
        lds[rb * 37 + q * 4 + 3] = v0.w;
        lds[(rb + 32) * 37 + q * 4 + 0] = v1.x;
        lds[(rb + 32) * 37 + q * 4 + 1] = v1.y;
        lds[(rb + 32) * 37 + q * 4 + 2] = v1.z;
        lds[(rb + 32) * 37 + q * 4 + 3] = v1.w;
        __syncthreads();
        if (ck < 31) {
            v0 = *(const float4*)&A0[(ck + 1) * 32 + q * 4];
            v1 = *(const float4*)&A1[(ck + 1) * 32 + q * 4];
        }
        #pragma unroll
        for (int d = 0; d < 32; ++d) {
            float av = lds[row * 37 + d];
            const float* wrow = &Wt[(ck * 32 + d) * T + grp * 8];
            #pragma unroll
            for (int t = 0; t < 8; ++t)
                acc[t] = fmaf(av, wrow[t], acc[t]);
        }
        __syncthreads();
    }

    float4* eo = (float4*)&e[(size_t)(row0 + row) * T + grp * 8];
    float4 o0, o1;
    o0.x = acc[0]; o0.y = acc[1]; o0.z = acc[2]; o0.w = acc[3];
    o1.x = acc[4]; o1.y = acc[5]; o1.z = acc[6]; o1.w = acc[7];
    eo[0] = o0; eo[1] = o1;
}

// ---------------- recursions ----------------
// blocks 0..127 alpha, 128..255 beta (verified, unchanged)
// blocks 256..383 viterbi: value-only forward using the sbuf row store as a
// broadcast (8x ds_read_b128 wave-uniform = conflict-free) + max3 tree;
// ballot-equality backtrace with TRANSPOSED trans copy (kills the 32-way
// bank conflict round 13 exposed: SQ_LDS_BANK_CONFLICT 4.05M).
__global__ __launch_bounds__(64) void k_rec(const float* __restrict__ e,
        const int* __restrict__ mask,
        const float* __restrict__ trans,
        const float* __restrict__ start,
        const float* __restrict__ endp,
        float* __restrict__ pa, float* __restrict__ pb,
        double* __restrict__ Ca, double* __restrict__ Cb,
        double* __restrict__ zd,
        float* __restrict__ tags_out)
{
    __shared__ __align__(16) char smem[78336];
    int bid = blockIdx.x;
    int tid = threadIdx.x;
    int j   = tid & 31;
    int r8 = tid >> 3, q = tid & 7;

    if (bid < 256) {
        int role = bid >> 7;     // 0=alpha, 1=beta
        int b    = bid & 127;
        float (*ebuf)[4096] = (float(*)[4096])smem;
        float (*pbuf)[4096] = (float(*)[4096])(smem + 32768);
        double (*cbuf)[128] = (double(*)[128])(smem + 65536);

        BALLOTS(ma, b);
        float Et[32];

        if (role == 0) {
            #pragma unroll
            for (int n = 0; n < 32; ++n) Et[n] = __expf(trans[n * T + j]);

            STAGEXP(0);
            float a0 = e[(0 * BATCH + b) * T + j] + start[j];
            float m = a0;
            #pragma unroll
            for (int d = 1; d < 32; d <<= 1) m = fmaxf(m, __shfl_xor(m, d));
            float v = __expf(a0 - m);
            float s = v;
            #pragma unroll
            for (int d = 1; d < 32; d <<= 1) s += __shfl_xor(s, d);
            float p = v / s;
            double C = (double)m + (double)__logf(s);
            if (tid < 32) pbuf[0][j] = p;
            if (tid == 0) cbuf[0][0] = C;

            for (int c = 0; c < 4; ++c) {
                int i0 = c ? c * 128 : 1, i1 = c * 128 + 127;
                for (int i = i0; i <= i1; ++i) {
                    float ee = ebuf[c & 1][(i & 127) * 32 + j];
                    float q_;
                    MATVEC32(q_, p, Et);
                    float vv = q_ * ee;
                    if (MB(ma, i)) p = vv;
                    if (tid < 32) pbuf[c & 1][(i & 127) * 32 + j] = p;
                    if (tid == 0) cbuf[c & 1][i & 127] = C;
                    if ((i & 7) == 0) {
                        float ss; RLSUM32(ss, p);
                        p = p / ss; C += (double)__logf(ss);
                    }
                }
                if (c < 3) STAGEXP(c + 1);
                FLUSHPC(pa, Ca, c);
            }
            float sz0 = p * __expf(endp[j]);
            float sz; RLSUM32(sz, sz0);
            if (tid == 0) zd[b] = C + (double)__logf(sz);
        } else {
            #pragma unroll
            for (int n = 0; n < 32; ++n) Et[n] = __expf(trans[j * T + n]);

            STAGEXP(3);
            float v0 = endp[j];
            float m = v0;
            #pragma unroll
            for (int d = 1; d < 32; d <<= 1) m = fmaxf(m, __shfl_xor(m, d));
            float v = __expf(v0 - m);
            float s = v;
            #pragma unroll
            for (int d = 1; d < 32; d <<= 1) s += __shfl_xor(s, d);
            float p = v / s;
            double C = (double)m + (double)__logf(s);
            if (tid < 32) pbuf[1][127 * 32 + j] = p;
            if (tid == 0) cbuf[1][127] = C;

            float een = ebuf[1][127 * 32 + j];
            for (int c = 0; c < 4; ++c) {
                int iS = 511 - 128 * c;
                int iE = (c < 3) ? (384 - 128 * c) : 1;
                for (int i = iS; i >= iE; --i) {
                    float ee = een;
                    if (i > iE)
                        een = ebuf[((i - 1) >> 7) & 1][((i - 1) & 127) * 32 + j];
                    float pe = p * ee;
                    float q_;
                    MATVEC32(q_, pe, Et);
                    if (MB(ma, i)) p = q_;
                    int orow = i - 1, lb = (orow >> 7) & 1;
                    if (tid < 32) pbuf[lb][(orow & 127) * 32 + j] = p;
                    if (tid == 0) cbuf[lb][orow & 127] = C;
                    if ((i & 7) == 0) {
                        float ss; RLSUM32(ss, p);
                        p = p / ss; C += (double)__logf(ss);
                    }
                }
                if (c < 3) {
                    STAGEXP(2 - c);
                    een = ebuf[(2 - c) & 1][127 * 32 + j];
                }
                FLUSHPC(pb, Cb, 3 - c);
            }
        }
    } else {
        // ---- viterbi ----
        int b2 = bid - 256;
        float* ebufv = (float*)smem;                       //  8 KB: 64 rows x 32
        float* sbuf  = (float*)(smem + 8192);              // 64 KB: 512 rows x 32
        float* tldsT = (float*)(smem + 73728);             //  4 KB: TRANSPOSED trans
        unsigned char* tagb = (unsigned char*)(smem + 77824);  // 512 B

        BALLOTS(ma, b2);

        // transposed copy: tldsT[j*32+n] = trans[n*T+j] (backtrace reads consecutive)
        #pragma unroll
        for (int k = 0; k < 16; ++k) {
            int idx = k * 64 + tid;
            int nn = idx >> 5, jj = idx & 31;
            tldsT[jj * 32 + nn] = trans[nn * T + jj];
        }

        float trv[32];
        #pragma unroll
        for (int n = 0; n < 32; ++n) trv[n] = trans[n * T + j];

        STAGEV(0);
        float sc = start[j] + ebufv[j];
        if (tid < 32) sbuf[j] = sc;        // row 0, single-writer

        // ---- forward: LDS-broadcast of previous row + max3 tree ----
        for (int c = 0; c < 8; ++c) {
            int i0 = c ? c * 64 : 1, i1 = c * 64 + 63;
            for (int i = i0; i <= i1; ++i) {
                const float4* srow = (const float4*)&sbuf[(i - 1) * 32];
                float ej = ebufv[(i & 63) * 32 + j];
                float cc[32];
                #pragma unroll
                for (int w4 = 0; w4 < 8; ++w4) {
                    float4 sv = srow[w4];       // wave-uniform addr -> broadcast
                    cc[4 * w4 + 0] = sv.x + trv[4 * w4 + 0];
                    cc[4 * w4 + 1] = sv.y + trv[4 * w4 + 1];
                    cc[4 * w4 + 2] = sv.z + trv[4 * w4 + 2];
                    cc[4 * w4 + 3] = sv.w + trv[4 * w4 + 3];
                }
                // max3-structured tree (max is exact under any association)
                float t[11];
                #pragma unroll
                for (int g = 0; g < 10; ++g)
                    t[g] = fmaxf(fmaxf(cc[3 * g], cc[3 * g + 1]), cc[3 * g + 2]);
                t[10] = fmaxf(cc[30], cc[31]);
                float u0 = fmaxf(fmaxf(t[0], t[1]), t[2]);
                float u1 = fmaxf(fmaxf(t[3], t[4]), t[5]);
                float u2 = fmaxf(fmaxf(t[6], t[7]), t[8]);
                float u3 = fmaxf(t[9], t[10]);
                float m_ = fmaxf(fmaxf(u0, u1), fmaxf(u2, u3));
                float v = m_ + ej;
                if (MB(ma, i)) sc = v;
                if (tid < 32) sbuf[i * 32 + j] = sc;   // single-writer, no conflict
            }
            if (c < 7) STAGEV(c + 1);
        }

        // final argmax over j (first index on ties)
        float fs = sc + endp[j];
        int fj = j;
        #pragma unroll
        for (int d = 1; d < 32; d <<= 1) {
            float ov = __shfl_xor(fs, d); int oj = __shfl_xor(fj, d);
            if (ov > fs || (ov == fs && oj < fj)) { fs = ov; fj = oj; }
        }
        int jstar = __builtin_amdgcn_readfirstlane(fj);
        tagb[SEQ - 1] = (unsigned char)jstar;

        // ---- backtrace: ballot equality on exact reference candidates ----
        int n = tid & 31;
        for (int c = 7; c >= 0; --c) {
            if (c < 7) STAGEV(c);           // ebufv <- chunk c (chunk 7 resident)
            int iS = c * 64 + 63, iE = c ? c * 64 : 1;
            for (int i = iS; i >= iE; --i) {
                float sn = sbuf[(i - 1) * 32 + n];          // jstar-independent
                float tn = tldsT[jstar * 32 + n];           // consecutive banks
                float en = ebufv[(i & 63) * 32 + jstar];    // broadcast
                float cn = (sn + tn) + en;   // reference add order
                float v;
                if (MB(ma, i)) {
                    v = sbuf[i * 32 + jstar];   // == max_n cn (mask=1)
                } else {
                    v = cn;                      // exact fallback: wave max
                    #pragma unroll
                    for (int d = 1; d < 32; d <<= 1)
                        v = fmaxf(v, __shfl_xor(v, d));
                }
                unsigned long long bm = __ballot(cn == v);
                jstar = (int)__builtin_ctzll(bm);   // first n (lanes 32-63 mirror)
                tagb[i - 1] = (unsigned char)jstar;
            }
        }
        #pragma unroll
        for (int k2 = 0; k2 < 8; ++k2) {
            int idx = k2 * 64 + tid;
            tags_out[(size_t)idx * BATCH + b2] = (float)tagb[idx];
        }
    }
}

// ---------------- probs = pa * pb * exp(Ca + Cb - z) ----------------
__global__ __launch_bounds__(256) void k_probs(const float* __restrict__ pa,
        const float* __restrict__ pb, const double* __restrict__ Ca,
        const double* __restrict__ Cb, const double* __restrict__ zd,
        float* __restrict__ out)
{
    int idx = blockIdx.x * 256 + threadIdx.x;
    int ib = idx >> 3;
    int b = ib & (BATCH - 1);
    double ex = Ca[ib] + Cb[ib] - zd[b];
    double scl = exp(ex);
    float4 a = ((const float4*)pa)[idx];
    float4 c = ((const float4*)pb)[idx];
    float4 o;
    o.x = (float)((double)a.x * (double)c.x * scl);
    o.y = (float)((double)a.y * (double)c.y * scl);
    o.z = (float)((double)a.z * (double)c.z * scl);
    o.w = (float)((double)a.w * (double)c.w * scl);
    ((float4*)out)[idx] = o;
}

extern "C" void kernel_launch(void* const* d_in, const int* in_sizes, int n_in,
                              void* d_out, int out_size, void* d_ws, size_t ws_size,
                              hipStream_t stream) {
    const float* features = (const float*)d_in[0];
    const int*   mask     = (const int*)d_in[1];
    const float* W        = (const float*)d_in[2];
    const float* bias     = (const float*)d_in[3];
    const float* trans    = (const float*)d_in[4];
    const float* startp   = (const float*)d_in[5];
    const float* endp     = (const float*)d_in[6];

    char* ws = (char*)d_ws;
    double* Ca = (double*)(ws + 0);
    double* Cb = (double*)(ws + 524288);
    double* zd = (double*)(ws + 1048576);
    float*  Wt = (float*)(ws + 1049600);
    float*  e  = (float*)(ws + 1180672);
    float*  pa = (float*)(ws + 9569280);
    float*  pb = (float*)(ws + 17957888);

    float* probs_out = (float*)d_out;
    float* tags_out  = probs_out + (size_t)SEQ * BATCH * T;

    k_wt<<<128, 256, 0, stream>>>(W, Wt);
    k_emis<<<1024, 256, 0, stream>>>(features, Wt, bias, e);
    k_rec<<<384, 64, 0, stream>>>(e, mask, trans, startp, endp,
                                  pa, pb, Ca, Cb, zd, tags_out);
    k_probs<<<2048, 256, 0, stream>>>(pa, pb, Ca, Cb, zd, probs_out);
}

// Round 15
// 288.790 us; speedup vs baseline: 2.3006x; 1.0884x over previous
//
#include <hip/hip_runtime.h>

#define SEQ 512
#define BATCH 128
#define DIM 1024
#define T 32

__device__ __forceinline__ float rlf(float x, int n) {
    return __int_as_float(__builtin_amdgcn_readlane(__float_as_int(x), n));
}

// wave-uniform mask bit: 512 bits in 8 u64 (SGPR-resident)
__device__ __forceinline__ int mbit(unsigned long long m0, unsigned long long m1,
        unsigned long long m2, unsigned long long m3, unsigned long long m4,
        unsigned long long m5, unsigned long long m6, unsigned long long m7, int i) {
    int w = i >> 6;
    unsigned long long cm =
        (w < 4) ? ((w < 2) ? (w == 0 ? m0 : m1) : (w == 2 ? m2 : m3))
                : ((w < 6) ? (w == 4 ? m4 : m5) : (w == 6 ? m6 : m7));
    return (int)((cm >> (i & 63)) & 1ULL);
}

#define BALLOTS(pre, bb) \
    unsigned long long pre##0 = __ballot(mask[(0 * 64 + tid) * BATCH + (bb)] != 0); \
    unsigned long long pre##1 = __ballot(mask[(1 * 64 + tid) * BATCH + (bb)] != 0); \
    unsigned long long pre##2 = __ballot(mask[(2 * 64 + tid) * BATCH + (bb)] != 0); \
    unsigned long long pre##3 = __ballot(mask[(3 * 64 + tid) * BATCH + (bb)] != 0); \
    unsigned long long pre##4 = __ballot(mask[(4 * 64 + tid) * BATCH + (bb)] != 0); \
    unsigned long long pre##5 = __ballot(mask[(5 * 64 + tid) * BATCH + (bb)] != 0); \
    unsigned long long pre##6 = __ballot(mask[(6 * 64 + tid) * BATCH + (bb)] != 0); \
    unsigned long long pre##7 = __ballot(mask[(7 * 64 + tid) * BATCH + (bb)] != 0);

#define MB(pre, i) mbit(pre##0, pre##1, pre##2, pre##3, pre##4, pre##5, pre##6, pre##7, (i))

#define RLSUM32(dst, src) { \
    float s0 = 0.f, s1 = 0.f, s2 = 0.f, s3 = 0.f; \
    _Pragma("unroll") \
    for (int n = 0; n < 8; ++n) { \
        s0 += rlf(src, 4 * n + 0); \
        s1 += rlf(src, 4 * n + 1); \
        s2 += rlf(src, 4 * n + 2); \
        s3 += rlf(src, 4 * n + 3); \
    } \
    dst = (s0 + s1) + (s2 + s3); }

// alpha/beta: stage 128 e-rows with exp applied
#define STAGEXP(blk) do { \
    _Pragma("unroll") \
    for (int ps = 0; ps < 16; ++ps) { \
        int r = ps * 8 + r8; \
        float4 v = *(const float4*)&e[(size_t)(((blk) * 128 + r) * BATCH + b) * T + q * 4]; \
        v.x = __expf(v.x); v.y = __expf(v.y); v.z = __expf(v.z); v.w = __expf(v.w); \
        *(float4*)&ebuf[(blk) & 1][r * 32 + q * 4] = v; \
    } } while (0)

#define FLUSHPC(dstP, dstC, blk) do { \
    _Pragma("unroll") \
    for (int ps = 0; ps < 16; ++ps) { \
        int r = ps * 8 + r8; \
        float4 v = *(const float4*)&pbuf[(blk) & 1][r * 32 + q * 4]; \
        *(float4*)&dstP[(size_t)(((blk) * 128 + r) * BATCH + b) * T + q * 4] = v; \
    } \
    _Pragma("unroll") \
    for (int ps = 0; ps < 2; ++ps) { \
        int r = ps * 64 + tid; \
        dstC[(size_t)((blk) * 128 + r) * BATCH + b] = cbuf[(blk) & 1][r]; \
    } } while (0)

// viterbi: stage 64 raw e-rows (single buffer)
#define STAGEV(blk) do { \
    _Pragma("unroll") \
    for (int ps = 0; ps < 8; ++ps) { \
        int r = ps * 8 + r8; \
        float4 v = *(const float4*)&e[(size_t)(((blk) * 64 + r) * BATCH + b2) * T + q * 4]; \
        *(float4*)&ebufv[r * 32 + q * 4] = v; \
    } } while (0)

// ---------------- W transpose ----------------
__global__ void k_wt(const float* __restrict__ W, float* __restrict__ Wt)
{
    int idx = blockIdx.x * 256 + threadIdx.x;
    if (idx >= DIM * T) return;
    int d = idx >> 5, t = idx & 31;
    Wt[idx] = W[t * DIM + d];
}

// ---------------- emissions (unchanged, verified) ----------------
__global__ __launch_bounds__(256) void k_emis(const float* __restrict__ A,
        const float* __restrict__ Wt, const float* __restrict__ bias,
        float* __restrict__ e)
{
    __shared__ float lds[64 * 37];
    int tid = threadIdx.x;
    int row0 = blockIdx.x * 64;
    int row = tid & 63;
    int grp = __builtin_amdgcn_readfirstlane(tid >> 6);
    int q = tid & 7;
    int rb = tid >> 3;

    float acc[8];
    #pragma unroll
    for (int t = 0; t < 8; ++t) acc[t] = bias[grp * 8 + t];

    const float* A0 = &A[(size_t)(row0 + rb) * DIM];
    const float* A1 = &A[(size_t)(row0 + rb + 32) * DIM];

    float4 v0 = *(const float4*)&A0[q * 4];
    float4 v1 = *(const float4*)&A1[q * 4];

    for (int ck = 0; ck < 32; ++ck) {
        lds[rb * 37 + q * 4 + 0] = v0.x;
        lds[rb * 37 + q * 4 + 1] = v0.y;
        lds[rb * 37 + q * 4 + 2] = v0.z;
        lds[rb * 37 + q * 4 + 3] = v0.w;
        lds[(rb + 32) * 37 + q * 4 + 0] = v1.x;
        lds[(rb + 32) * 37 + q * 4 + 1] = v1.y;
        lds[(rb + 32) * 37 + q * 4 + 2] = v1.z;
        lds[(rb + 32) * 37 + q * 4 + 3] = v1.w;
        __syncthreads();
        if (ck < 31) {
            v0 = *(const float4*)&A0[(ck + 1) * 32 + q * 4];
            v1 = *(const float4*)&A1[(ck + 1) * 32 + q * 4];
        }
        #pragma unroll
        for (int d = 0; d < 32; ++d) {
            float av = lds[row * 37 + d];
            const float* wrow = &Wt[(ck * 32 + d) * T + grp * 8];
            #pragma unroll
            for (int t = 0; t < 8; ++t)
                acc[t] = fmaf(av, wrow[t], acc[t]);
        }
        __syncthreads();
    }

    float4* eo = (float4*)&e[(size_t)(row0 + row) * T + grp * 8];
    float4 o0, o1;
    o0.x = acc[0]; o0.y = acc[1]; o0.z = acc[2]; o0.w = acc[3];
    o1.x = acc[4]; o1.y = acc[5]; o1.z = acc[6]; o1.w = acc[7];
    eo[0] = o0; eo[1] = o1;
}

// ---------------- recursions ----------------
// Half-split matvec/scan: lane (h=tid>>5, j=tid&31) handles sources 16h..16h+15
// via 4x ds_read_b128 of the previous row (pbuf/sbuf double as broadcast),
// then one shfl_xor(32) combine. Rescale moved BEFORE the row/C write so the
// LDS row feeds the recursion consistently (p/ss paired with C+log ss).
__global__ __launch_bounds__(64) void k_rec(const float* __restrict__ e,
        const int* __restrict__ mask,
        const float* __restrict__ trans,
        const float* __restrict__ start,
        const float* __restrict__ endp,
        float* __restrict__ pa, float* __restrict__ pb,
        double* __restrict__ Ca, double* __restrict__ Cb,
        double* __restrict__ zd,
        float* __restrict__ tags_out)
{
    __shared__ __align__(16) char smem[78336];
    int bid = blockIdx.x;
    int tid = threadIdx.x;
    int j   = tid & 31;
    int h   = tid >> 5;          // source half
    int r8 = tid >> 3, q = tid & 7;

    if (bid < 256) {
        int role = bid >> 7;     // 0=alpha, 1=beta
        int b    = bid & 127;
        float (*ebuf)[4096] = (float(*)[4096])smem;
        float (*pbuf)[4096] = (float(*)[4096])(smem + 32768);
        double (*cbuf)[128] = (double(*)[128])(smem + 65536);

        BALLOTS(ma, b);
        float Eh[16];

        if (role == 0) {
            // ---- alpha: Eh[m] = exp(trans[16h+m][j]) ----
            #pragma unroll
            for (int m = 0; m < 16; ++m)
                Eh[m] = __expf(trans[(16 * h + m) * T + j]);

            STAGEXP(0);
            float a0 = e[(0 * BATCH + b) * T + j] + start[j];
            float m = a0;
            #pragma unroll
            for (int d = 1; d < 32; d <<= 1) m = fmaxf(m, __shfl_xor(m, d));
            float v = __expf(a0 - m);
            float s = v;
            #pragma unroll
            for (int d = 1; d < 32; d <<= 1) s += __shfl_xor(s, d);
            float p = v / s;
            double C = (double)m + (double)__logf(s);
            if (tid < 32) pbuf[0][j] = p;
            if (tid == 0) cbuf[0][0] = C;

            for (int c = 0; c < 4; ++c) {
                int i0 = c ? c * 128 : 1, i1 = c * 128 + 127;
                for (int i = i0; i <= i1; ++i) {
                    int pr = i - 1;
                    const float4* pr4 = (const float4*)&pbuf[(pr >> 7) & 1][(pr & 127) * 32 + 16 * h];
                    float ee = ebuf[c & 1][(i & 127) * 32 + j];
                    float4 x0 = pr4[0], x1 = pr4[1], x2 = pr4[2], x3 = pr4[3];
                    float q0 = fmaf(x0.w, Eh[3], fmaf(x0.z, Eh[2], fmaf(x0.y, Eh[1], x0.x * Eh[0])));
                    float q1 = fmaf(x1.w, Eh[7], fmaf(x1.z, Eh[6], fmaf(x1.y, Eh[5], x1.x * Eh[4])));
                    float q2 = fmaf(x2.w, Eh[11], fmaf(x2.z, Eh[10], fmaf(x2.y, Eh[9], x2.x * Eh[8])));
                    float q3 = fmaf(x3.w, Eh[15], fmaf(x3.z, Eh[14], fmaf(x3.y, Eh[13], x3.x * Eh[12])));
                    float qh = (q0 + q1) + (q2 + q3);
                    float qq = qh + __shfl_xor(qh, 32);
                    float vv = qq * ee;
                    if (MB(ma, i)) p = vv;
                    if ((i & 7) == 0) {          // rescale BEFORE write (compensated pair)
                        float ss; RLSUM32(ss, p);
                        p = p / ss; C += (double)__logf(ss);
                    }
                    if (tid < 32) pbuf[c & 1][(i & 127) * 32 + j] = p;
                    if (tid == 0) cbuf[c & 1][i & 127] = C;
                }
                if (c < 3) STAGEXP(c + 1);
                FLUSHPC(pa, Ca, c);
            }
            float sz0 = p * __expf(endp[j]);
            float sz; RLSUM32(sz, sz0);
            if (tid == 0) zd[b] = C + (double)__logf(sz);
        } else {
            // ---- beta: Eh[m] = exp(trans[j][16h+m]) ----
            #pragma unroll
            for (int m = 0; m < 16; ++m)
                Eh[m] = __expf(trans[j * T + 16 * h + m]);

            STAGEXP(3);
            float v0 = endp[j];
            float m = v0;
            #pragma unroll
            for (int d = 1; d < 32; d <<= 1) m = fmaxf(m, __shfl_xor(m, d));
            float v = __expf(v0 - m);
            float s = v;
            #pragma unroll
            for (int d = 1; d < 32; d <<= 1) s += __shfl_xor(s, d);
            float p = v / s;
            double C = (double)m + (double)__logf(s);
            if (tid < 32) pbuf[1][127 * 32 + j] = p;
            if (tid == 0) cbuf[1][127] = C;

            for (int c = 0; c < 4; ++c) {
                int iS = 511 - 128 * c;
                int iE = (c < 3) ? (384 - 128 * c) : 1;
                for (int i = iS; i >= iE; --i) {
                    int bI = (i >> 7) & 1;
                    const float4* pr4 = (const float4*)&pbuf[bI][(i & 127) * 32 + 16 * h];
                    const float4* er4 = (const float4*)&ebuf[bI][(i & 127) * 32 + 16 * h];
                    float4 pv0 = pr4[0], pv1 = pr4[1], pv2 = pr4[2], pv3 = pr4[3];
                    float4 ev0 = er4[0], ev1 = er4[1], ev2 = er4[2], ev3 = er4[3];
                    float q0 = fmaf(pv0.w * ev0.w, Eh[3], fmaf(pv0.z * ev0.z, Eh[2],
                                fmaf(pv0.y * ev0.y, Eh[1], (pv0.x * ev0.x) * Eh[0])));
                    float q1 = fmaf(pv1.w * ev1.w, Eh[7], fmaf(pv1.z * ev1.z, Eh[6],
                                fmaf(pv1.y * ev1.y, Eh[5], (pv1.x * ev1.x) * Eh[4])));
                    float q2 = fmaf(pv2.w * ev2.w, Eh[11], fmaf(pv2.z * ev2.z, Eh[10],
                                fmaf(pv2.y * ev2.y, Eh[9], (pv2.x * ev2.x) * Eh[8])));
                    float q3 = fmaf(pv3.w * ev3.w, Eh[15], fmaf(pv3.z * ev3.z, Eh[14],
                                fmaf(pv3.y * ev3.y, Eh[13], (pv3.x * ev3.x) * Eh[12])));
                    float qh = (q0 + q1) + (q2 + q3);
                    float qq = qh + __shfl_xor(qh, 32);
                    if (MB(ma, i)) p = qq;
                    if ((i & 7) == 0) {
                        float ss; RLSUM32(ss, p);
                        p = p / ss; C += (double)__logf(ss);
                    }
                    int orow = i - 1, lb = (orow >> 7) & 1;
                    if (tid < 32) pbuf[lb][(orow & 127) * 32 + j] = p;
                    if (tid == 0) cbuf[lb][orow & 127] = C;
                }
                if (c < 3) STAGEXP(2 - c);
                FLUSHPC(pb, Cb, 3 - c);
            }
        }
    } else {
        // ---- viterbi: half-split value-only forward + ballot backtrace ----
        int b2 = bid - 256;
        float* ebufv = (float*)smem;                       //  8 KB: 64 rows x 32
        float* sbuf  = (float*)(smem + 8192);              // 64 KB: 512 rows x 32
        float* tldsT = (float*)(smem + 73728);             //  4 KB: transposed trans
        unsigned char* tagb = (unsigned char*)(smem + 77824);  // 512 B

        BALLOTS(ma, b2);

        #pragma unroll
        for (int k = 0; k < 16; ++k) {
            int idx = k * 64 + tid;
            int nn = idx >> 5, jj = idx & 31;
            tldsT[jj * 32 + nn] = trans[nn * T + jj];
        }

        float trvh[16];
        #pragma unroll
        for (int m = 0; m < 16; ++m)
            trvh[m] = trans[(16 * h + m) * T + j];

        STAGEV(0);
        float sc = start[j] + ebufv[j];
        if (tid < 32) sbuf[j] = sc;

        for (int c = 0; c < 8; ++c) {
            int i0 = c ? c * 64 : 1, i1 = c * 64 + 63;
            for (int i = i0; i <= i1; ++i) {
                const float4* sr4 = (const float4*)&sbuf[(i - 1) * 32 + 16 * h];
                float ej = ebufv[(i & 63) * 32 + j];
                float4 s0 = sr4[0], s1 = sr4[1], s2 = sr4[2], s3 = sr4[3];
                float m0 = fmaxf(fmaxf(s0.x + trvh[0], s0.y + trvh[1]),
                                 fmaxf(s0.z + trvh[2], s0.w + trvh[3]));
                float m1 = fmaxf(fmaxf(s1.x + trvh[4], s1.y + trvh[5]),
                                 fmaxf(s1.z + trvh[6], s1.w + trvh[7]));
                float m2 = fmaxf(fmaxf(s2.x + trvh[8], s2.y + trvh[9]),
                                 fmaxf(s2.z + trvh[10], s2.w + trvh[11]));
                float m3 = fmaxf(fmaxf(s3.x + trvh[12], s3.y + trvh[13]),
                                 fmaxf(s3.z + trvh[14], s3.w + trvh[15]));
                float mh = fmaxf(fmaxf(m0, m1), fmaxf(m2, m3));
                float mm = fmaxf(mh, __shfl_xor(mh, 32));   // max exact, any shape
                float v = mm + ej;
                if (MB(ma, i)) sc = v;
                if (tid < 32) sbuf[i * 32 + j] = sc;
            }
            if (c < 7) STAGEV(c + 1);
        }

        // final argmax over j (first index on ties)
        float fs = sc + endp[j];
        int fj = j;
        #pragma unroll
        for (int d = 1; d < 32; d <<= 1) {
            float ov = __shfl_xor(fs, d); int oj = __shfl_xor(fj, d);
            if (ov > fs || (ov == fs && oj < fj)) { fs = ov; fj = oj; }
        }
        int jstar = __builtin_amdgcn_readfirstlane(fj);
        tagb[SEQ - 1] = (unsigned char)jstar;

        // backtrace: ballot equality on exact reference candidates
        int n = tid & 31;
        for (int c = 7; c >= 0; --c) {
            if (c < 7) STAGEV(c);
            int iS = c * 64 + 63, iE = c ? c * 64 : 1;
            for (int i = iS; i >= iE; --i) {
                float sn = sbuf[(i - 1) * 32 + n];
                float tn = tldsT[jstar * 32 + n];
                float en = ebufv[(i & 63) * 32 + jstar];
                float cn = (sn + tn) + en;
                float v;
                if (MB(ma, i)) {
                    v = sbuf[i * 32 + jstar];
                } else {
                    v = cn;
                    #pragma unroll
                    for (int d = 1; d < 32; d <<= 1)
                        v = fmaxf(v, __shfl_xor(v, d));
                }
                unsigned long long bm = __ballot(cn == v);
                jstar = (int)__builtin_ctzll(bm);
                tagb[i - 1] = (unsigned char)jstar;
            }
        }
        #pragma unroll
        for (int k2 = 0; k2 < 8; ++k2) {
            int idx = k2 * 64 + tid;
            tags_out[(size_t)idx * BATCH + b2] = (float)tagb[idx];
        }
    }
}

// ---------------- probs = pa * pb * exp(Ca + Cb - z) ----------------
__global__ __launch_bounds__(256) void k_probs(const float* __restrict__ pa,
        const float* __restrict__ pb, const double* __restrict__ Ca,
        const double* __restrict__ Cb, const double* __restrict__ zd,
        float* __restrict__ out)
{
    int idx = blockIdx.x * 256 + threadIdx.x;
    int ib = idx >> 3;
    int b = ib & (BATCH - 1);
    double ex = Ca[ib] + Cb[ib] - zd[b];
    double scl = exp(ex);
    float4 a = ((const float4*)pa)[idx];
    float4 c = ((const float4*)pb)[idx];
    float4 o;
    o.x = (float)((double)a.x * (double)c.x * scl);
    o.y = (float)((double)a.y * (double)c.y * scl);
    o.z = (float)((double)a.z * (double)c.z * scl);
    o.w = (float)((double)a.w * (double)c.w * scl);
    ((float4*)out)[idx] = o;
}

extern "C" void kernel_launch(void* const* d_in, const int* in_sizes, int n_in,
                              void* d_out, int out_size, void* d_ws, size_t ws_size,
                              hipStream_t stream) {
    const float* features = (const float*)d_in[0];
    const int*   mask     = (const int*)d_in[1];
    const float* W        = (const float*)d_in[2];
    const float* bias     = (const float*)d_in[3];
    const float* trans    = (const float*)d_in[4];
    const float* startp   = (const float*)d_in[5];
    const float* endp     = (const float*)d_in[6];

    char* ws = (char*)d_ws;
    double* Ca = (double*)(ws + 0);
    double* Cb = (double*)(ws + 524288);
    double* zd = (double*)(ws + 1048576);
    float*  Wt = (float*)(ws + 1049600);
    float*  e  = (float*)(ws + 1180672);
    float*  pa = (float*)(ws + 9569280);
    float*  pb = (float*)(ws + 17957888);

    float* probs_out = (float*)d_out;
    float* tags_out  = probs_out + (size_t)SEQ * BATCH * T;

    k_wt<<<128, 256, 0, stream>>>(W, Wt);
    k_emis<<<1024, 256, 0, stream>>>(features, Wt, bias, e);
    k_rec<<<384, 64, 0, stream>>>(e, mask, trans, startp, endp,
                                  pa, pb, Ca, Cb, zd, tags_out);
    k_probs<<<2048, 256, 0, stream>>>(pa, pb, Ca, Cb, zd, probs_out);
}

// Round 16
// 287.411 us; speedup vs baseline: 2.3117x; 1.0048x over previous
//
#include <hip/hip_runtime.h>

#define SEQ 512
#define BATCH 128
#define DIM 1024
#define T 32

typedef int v2i_ __attribute__((ext_vector_type(2)));

__device__ __forceinline__ float rlf(float x, int n) {
    return __int_as_float(__builtin_amdgcn_readlane(__float_as_int(x), n));
}

// cross-half combine via permlane32_swap (VALU, not DS). r.x/r.y hold the
// two halves' values (order-immune for + and max).
__device__ __forceinline__ float sum_halves(float x) {
    v2i_ r = __builtin_amdgcn_permlane32_swap(__float_as_int(x), __float_as_int(x), false, false);
    return __int_as_float(r.x) + __int_as_float(r.y);
}
__device__ __forceinline__ float max_halves(float x) {
    v2i_ r = __builtin_amdgcn_permlane32_swap(__float_as_int(x), __float_as_int(x), false, false);
    return fmaxf(__int_as_float(r.x), __int_as_float(r.y));
}

// wave-uniform mask bit: 512 bits in 8 u64 (SGPR-resident)
__device__ __forceinline__ int mbit(unsigned long long m0, unsigned long long m1,
        unsigned long long m2, unsigned long long m3, unsigned long long m4,
        unsigned long long m5, unsigned long long m6, unsigned long long m7, int i) {
    int w = i >> 6;
    unsigned long long cm =
        (w < 4) ? ((w < 2) ? (w == 0 ? m0 : m1) : (w == 2 ? m2 : m3))
                : ((w < 6) ? (w == 4 ? m4 : m5) : (w == 6 ? m6 : m7));
    return (int)((cm >> (i & 63)) & 1ULL);
}

#define BALLOTS(pre, bb) \
    unsigned long long pre##0 = __ballot(mask[(0 * 64 + tid) * BATCH + (bb)] != 0); \
    unsigned long long pre##1 = __ballot(mask[(1 * 64 + tid) * BATCH + (bb)] != 0); \
    unsigned long long pre##2 = __ballot(mask[(2 * 64 + tid) * BATCH + (bb)] != 0); \
    unsigned long long pre##3 = __ballot(mask[(3 * 64 + tid) * BATCH + (bb)] != 0); \
    unsigned long long pre##4 = __ballot(mask[(4 * 64 + tid) * BATCH + (bb)] != 0); \
    unsigned long long pre##5 = __ballot(mask[(5 * 64 + tid) * BATCH + (bb)] != 0); \
    unsigned long long pre##6 = __ballot(mask[(6 * 64 + tid) * BATCH + (bb)] != 0); \
    unsigned long long pre##7 = __ballot(mask[(7 * 64 + tid) * BATCH + (bb)] != 0);

#define MB(pre, i) mbit(pre##0, pre##1, pre##2, pre##3, pre##4, pre##5, pre##6, pre##7, (i))

#define RLSUM32(dst, src) { \
    float s0 = 0.f, s1 = 0.f, s2 = 0.f, s3 = 0.f; \
    _Pragma("unroll") \
    for (int n = 0; n < 8; ++n) { \
        s0 += rlf(src, 4 * n + 0); \
        s1 += rlf(src, 4 * n + 1); \
        s2 += rlf(src, 4 * n + 2); \
        s3 += rlf(src, 4 * n + 3); \
    } \
    dst = (s0 + s1) + (s2 + s3); }

// alpha/beta: stage 128 e-rows with exp applied
#define STAGEXP(blk) do { \
    _Pragma("unroll") \
    for (int ps = 0; ps < 16; ++ps) { \
        int r = ps * 8 + r8; \
        float4 v = *(const float4*)&e[(size_t)(((blk) * 128 + r) * BATCH + b) * T + q * 4]; \
        v.x = __expf(v.x); v.y = __expf(v.y); v.z = __expf(v.z); v.w = __expf(v.w); \
        *(float4*)&ebuf[(blk) & 1][r * 32 + q * 4] = v; \
    } } while (0)

#define FLUSHPC(dstP, dstC, blk) do { \
    _Pragma("unroll") \
    for (int ps = 0; ps < 16; ++ps) { \
        int r = ps * 8 + r8; \
        float4 v = *(const float4*)&pbuf[(blk) & 1][r * 32 + q * 4]; \
        *(float4*)&dstP[(size_t)(((blk) * 128 + r) * BATCH + b) * T + q * 4] = v; \
    } \
    _Pragma("unroll") \
    for (int ps = 0; ps < 2; ++ps) { \
        int r = ps * 64 + tid; \
        dstC[(size_t)((blk) * 128 + r) * BATCH + b] = cbuf[(blk) & 1][r]; \
    } } while (0)

// viterbi: stage 64 raw e-rows (single buffer)
#define STAGEV(blk) do { \
    _Pragma("unroll") \
    for (int ps = 0; ps < 8; ++ps) { \
        int r = ps * 8 + r8; \
        float4 v = *(const float4*)&e[(size_t)(((blk) * 64 + r) * BATCH + b2) * T + q * 4]; \
        *(float4*)&ebufv[r * 32 + q * 4] = v; \
    } } while (0)

// ---------------- W transpose ----------------
__global__ void k_wt(const float* __restrict__ W, float* __restrict__ Wt)
{
    int idx = blockIdx.x * 256 + threadIdx.x;
    if (idx >= DIM * T) return;
    int d = idx >> 5, t = idx & 31;
    Wt[idx] = W[t * DIM + d];
}

// ---------------- emissions (unchanged, verified) ----------------
__global__ __launch_bounds__(256) void k_emis(const float* __restrict__ A,
        const float* __restrict__ Wt, const float* __restrict__ bias,
        float* __restrict__ e)
{
    __shared__ float lds[64 * 37];
    int tid = threadIdx.x;
    int row0 = blockIdx.x * 64;
    int row = tid & 63;
    int grp = __builtin_amdgcn_readfirstlane(tid >> 6);
    int q = tid & 7;
    int rb = tid >> 3;

    float acc[8];
    #pragma unroll
    for (int t = 0; t < 8; ++t) acc[t] = bias[grp * 8 + t];

    const float* A0 = &A[(size_t)(row0 + rb) * DIM];
    const float* A1 = &A[(size_t)(row0 + rb + 32) * DIM];

    float4 v0 = *(const float4*)&A0[q * 4];
    float4 v1 = *(const float4*)&A1[q * 4];

    for (int ck = 0; ck < 32; ++ck) {
        lds[rb * 37 + q * 4 + 0] = v0.x;
        lds[rb * 37 + q * 4 + 1] = v0.y;
        lds[rb * 37 + q * 4 + 2] = v0.z;
        lds[rb * 37 + q * 4 + 3] = v0.w;
        lds[(rb + 32) * 37 + q * 4 + 0] = v1.x;
        lds[(rb + 32) * 37 + q * 4 + 1] = v1.y;
        lds[(rb + 32) * 37 + q * 4 + 2] = v1.z;
        lds[(rb + 32) * 37 + q * 4 + 3] = v1.w;
        __syncthreads();
        if (ck < 31) {
            v0 = *(const float4*)&A0[(ck + 1) * 32 + q * 4];
            v1 = *(const float4*)&A1[(ck + 1) * 32 + q * 4];
        }
        #pragma unroll
        for (int d = 0; d < 32; ++d) {
            float av = lds[row * 37 + d];
            const float* wrow = &Wt[(ck * 32 + d) * T + grp * 8];
            #pragma unroll
            for (int t = 0; t < 8; ++t)
                acc[t] = fmaf(av, wrow[t], acc[t]);
        }
        __syncthreads();
    }

    float4* eo = (float4*)&e[(size_t)(row0 + row) * T + grp * 8];
    float4 o0, o1;
    o0.x = acc[0]; o0.y = acc[1]; o0.z = acc[2]; o0.w = acc[3];
    o1.x = acc[4]; o1.y = acc[5]; o1.z = acc[6]; o1.w = acc[7];
    eo[0] = o0; eo[1] = o1;
}

// ---------------- recursions ----------------
// Half-split matvec/scan (round 15) with: per-step cross-half combine via
// permlane32_swap (VALU, off the DS latency path), beta pe-ring (pre-multiplied
// p*ee row: 4 ds_reads instead of 8 + 16 muls), and unguarded row writes
// (both halves identical -> same-addr same-value, 2-way free).
__global__ __launch_bounds__(64) void k_rec(const float* __restrict__ e,
        const int* __restrict__ mask,
        const float* __restrict__ trans,
        const float* __restrict__ start,
        const float* __restrict__ endp,
        float* __restrict__ pa, float* __restrict__ pb,
        double* __restrict__ Ca, double* __restrict__ Cb,
        double* __restrict__ zd,
        float* __restrict__ tags_out)
{
    __shared__ __align__(16) char smem[78336];
    int bid = blockIdx.x;
    int tid = threadIdx.x;
    int j   = tid & 31;
    int h   = tid >> 5;          // source half
    int r8 = tid >> 3, q = tid & 7;

    if (bid < 256) {
        int role = bid >> 7;     // 0=alpha, 1=beta
        int b    = bid & 127;
        float (*ebuf)[4096] = (float(*)[4096])smem;
        float (*pbuf)[4096] = (float(*)[4096])(smem + 32768);
        double (*cbuf)[128] = (double(*)[128])(smem + 65536);
        float* pering = (float*)(smem + 67584);   // 2 rows x 32 (beta only)

        BALLOTS(ma, b);
        float Eh[16];

        if (role == 0) {
            // ---- alpha: Eh[m] = exp(trans[16h+m][j]) ----
            #pragma unroll
            for (int m = 0; m < 16; ++m)
                Eh[m] = __expf(trans[(16 * h + m) * T + j]);

            STAGEXP(0);
            float a0 = e[(0 * BATCH + b) * T + j] + start[j];
            float m = a0;
            #pragma unroll
            for (int d = 1; d < 32; d <<= 1) m = fmaxf(m, __shfl_xor(m, d));
            float v = __expf(a0 - m);
            float s = v;
            #pragma unroll
            for (int d = 1; d < 32; d <<= 1) s += __shfl_xor(s, d);
            float p = v / s;
            double C = (double)m + (double)__logf(s);
            pbuf[0][j] = p;
            if (tid == 0) cbuf[0][0] = C;

            for (int c = 0; c < 4; ++c) {
                int i0 = c ? c * 128 : 1, i1 = c * 128 + 127;
                for (int i = i0; i <= i1; ++i) {
                    int pr = i - 1;
                    const float4* pr4 = (const float4*)&pbuf[(pr >> 7) & 1][(pr & 127) * 32 + 16 * h];
                    float ee = ebuf[c & 1][(i & 127) * 32 + j];
                    float4 x0 = pr4[0], x1 = pr4[1], x2 = pr4[2], x3 = pr4[3];
                    float q0 = fmaf(x0.w, Eh[3], fmaf(x0.z, Eh[2], fmaf(x0.y, Eh[1], x0.x * Eh[0])));
                    float q1 = fmaf(x1.w, Eh[7], fmaf(x1.z, Eh[6], fmaf(x1.y, Eh[5], x1.x * Eh[4])));
                    float q2 = fmaf(x2.w, Eh[11], fmaf(x2.z, Eh[10], fmaf(x2.y, Eh[9], x2.x * Eh[8])));
                    float q3 = fmaf(x3.w, Eh[15], fmaf(x3.z, Eh[14], fmaf(x3.y, Eh[13], x3.x * Eh[12])));
                    float qh = (q0 + q1) + (q2 + q3);
                    float qq = sum_halves(qh);
                    float vv = qq * ee;
                    if (MB(ma, i)) p = vv;
                    if ((i & 7) == 0) {          // rescale BEFORE write (compensated pair)
                        float ss; RLSUM32(ss, p);
                        p = p / ss; C += (double)__logf(ss);
                    }
                    pbuf[c & 1][(i & 127) * 32 + j] = p;
                    if (tid == 0) cbuf[c & 1][i & 127] = C;
                }
                if (c < 3) STAGEXP(c + 1);
                FLUSHPC(pa, Ca, c);
            }
            float sz0 = p * __expf(endp[j]);
            float sz; RLSUM32(sz, sz0);
            if (tid == 0) zd[b] = C + (double)__logf(sz);
        } else {
            // ---- beta: Eh[m] = exp(trans[j][16h+m]) ----
            #pragma unroll
            for (int m = 0; m < 16; ++m)
                Eh[m] = __expf(trans[j * T + 16 * h + m]);

            STAGEXP(3);
            float v0 = endp[j];
            float m = v0;
            #pragma unroll
            for (int d = 1; d < 32; d <<= 1) m = fmaxf(m, __shfl_xor(m, d));
            float v = __expf(v0 - m);
            float s = v;
            #pragma unroll
            for (int d = 1; d < 32; d <<= 1) s += __shfl_xor(s, d);
            float p = v / s;
            double C = (double)m + (double)__logf(s);
            pbuf[1][127 * 32 + j] = p;
            if (tid == 0) cbuf[1][127] = C;
            pering[32 + j] = p * ebuf[1][127 * 32 + j];   // ring row (511&1)=1

            for (int c = 0; c < 4; ++c) {
                int iS = 511 - 128 * c;
                int iE = (c < 3) ? (384 - 128 * c) : 1;
                for (int i = iS; i >= iE; --i) {
                    const float4* pe4 = (const float4*)&pering[(i & 1) * 32 + 16 * h];
                    float4 x0 = pe4[0], x1 = pe4[1], x2 = pe4[2], x3 = pe4[3];
                    float q0 = fmaf(x0.w, Eh[3], fmaf(x0.z, Eh[2], fmaf(x0.y, Eh[1], x0.x * Eh[0])));
                    float q1 = fmaf(x1.w, Eh[7], fmaf(x1.z, Eh[6], fmaf(x1.y, Eh[5], x1.x * Eh[4])));
                    float q2 = fmaf(x2.w, Eh[11], fmaf(x2.z, Eh[10], fmaf(x2.y, Eh[9], x2.x * Eh[8])));
                    float q3 = fmaf(x3.w, Eh[15], fmaf(x3.z, Eh[14], fmaf(x3.y, Eh[13], x3.x * Eh[12])));
                    float qh = (q0 + q1) + (q2 + q3);
                    float qq = sum_halves(qh);
                    if (MB(ma, i)) p = qq;
                    if ((i & 7) == 0) {
                        float ss; RLSUM32(ss, p);
                        p = p / ss; C += (double)__logf(ss);
                    }
                    int orow = i - 1, lb = (orow >> 7) & 1;
                    pbuf[lb][(orow & 127) * 32 + j] = p;
                    if (tid == 0) cbuf[lb][orow & 127] = C;
                    if (i > iE) {   // in-chunk ring refill: pe for row i-1
                        float ee = ebuf[((i - 1) >> 7) & 1][((i - 1) & 127) * 32 + j];
                        pering[((i - 1) & 1) * 32 + j] = p * ee;
                    }
                }
                if (c < 3) {
                    STAGEXP(2 - c);                          // stage chunk holding row iE-1
                    float ee = ebuf[(2 - c) & 1][127 * 32 + j];
                    pering[((iE - 1) & 1) * 32 + j] = p * ee;
                }
                FLUSHPC(pb, Cb, 3 - c);
            }
        }
    } else {
        // ---- viterbi: half-split value-only forward + ballot backtrace ----
        int b2 = bid - 256;
        float* ebufv = (float*)smem;                       //  8 KB: 64 rows x 32
        float* sbuf  = (float*)(smem + 8192);              // 64 KB: 512 rows x 32
        float* tldsT = (float*)(smem + 73728);             //  4 KB: transposed trans
        unsigned char* tagb = (unsigned char*)(smem + 77824);  // 512 B

        BALLOTS(ma, b2);

        #pragma unroll
        for (int k = 0; k < 16; ++k) {
            int idx = k * 64 + tid;
            int nn = idx >> 5, jj = idx & 31;
            tldsT[jj * 32 + nn] = trans[nn * T + jj];
        }

        float trvh[16];
        #pragma unroll
        for (int m = 0; m < 16; ++m)
            trvh[m] = trans[(16 * h + m) * T + j];

        STAGEV(0);
        float sc = start[j] + ebufv[j];
        sbuf[j] = sc;

        for (int c = 0; c < 8; ++c) {
            int i0 = c ? c * 64 : 1, i1 = c * 64 + 63;
            for (int i = i0; i <= i1; ++i) {
                const float4* sr4 = (const float4*)&sbuf[(i - 1) * 32 + 16 * h];
                float ej = ebufv[(i & 63) * 32 + j];
                float4 s0 = sr4[0], s1 = sr4[1], s2 = sr4[2], s3 = sr4[3];
                float m0 = fmaxf(fmaxf(s0.x + trvh[0], s0.y + trvh[1]),
                                 fmaxf(s0.z + trvh[2], s0.w + trvh[3]));
                float m1 = fmaxf(fmaxf(s1.x + trvh[4], s1.y + trvh[5]),
                                 fmaxf(s1.z + trvh[6], s1.w + trvh[7]));
                float m2 = fmaxf(fmaxf(s2.x + trvh[8], s2.y + trvh[9]),
                                 fmaxf(s2.z + trvh[10], s2.w + trvh[11]));
                float m3 = fmaxf(fmaxf(s3.x + trvh[12], s3.y + trvh[13]),
                                 fmaxf(s3.z + trvh[14], s3.w + trvh[15]));
                float mh = fmaxf(fmaxf(m0, m1), fmaxf(m2, m3));
                float mm = max_halves(mh);      // max exact, any shape
                float v = mm + ej;
                if (MB(ma, i)) sc = v;
                sbuf[i * 32 + j] = sc;
            }
            if (c < 7) STAGEV(c + 1);
        }

        // final argmax over j (first index on ties)
        float fs = sc + endp[j];
        int fj = j;
        #pragma unroll
        for (int d = 1; d < 32; d <<= 1) {
            float ov = __shfl_xor(fs, d); int oj = __shfl_xor(fj, d);
            if (ov > fs || (ov == fs && oj < fj)) { fs = ov; fj = oj; }
        }
        int jstar = __builtin_amdgcn_readfirstlane(fj);
        tagb[SEQ - 1] = (unsigned char)jstar;

        // backtrace: ballot equality on exact reference candidates
        int n = tid & 31;
        for (int c = 7; c >= 0; --c) {
            if (c < 7) STAGEV(c);
            int iS = c * 64 + 63, iE = c ? c * 64 : 1;
            for (int i = iS; i >= iE; --i) {
                float sn = sbuf[(i - 1) * 32 + n];
                float tn = tldsT[jstar * 32 + n];
                float en = ebufv[(i & 63) * 32 + jstar];
                float cn = (sn + tn) + en;
                float v;
                if (MB(ma, i)) {
                    v = sbuf[i * 32 + jstar];
                } else {
                    v = cn;
                    #pragma unroll
                    for (int d = 1; d < 32; d <<= 1)
                        v = fmaxf(v, __shfl_xor(v, d));
                }
                unsigned long long bm = __ballot(cn == v);
                jstar = (int)__builtin_ctzll(bm);
                tagb[i - 1] = (unsigned char)jstar;
            }
        }
        #pragma unroll
        for (int k2 = 0; k2 < 8; ++k2) {
            int idx = k2 * 64 + tid;
            tags_out[(size_t)idx * BATCH + b2] = (float)tagb[idx];
        }
    }
}

// ---------------- probs = pa * pb * exp(Ca + Cb - z) ----------------
__global__ __launch_bounds__(256) void k_probs(const float* __restrict__ pa,
        const float* __restrict__ pb, const double* __restrict__ Ca,
        const double* __restrict__ Cb, const double* __restrict__ zd,
        float* __restrict__ out)
{
    int idx = blockIdx.x * 256 + threadIdx.x;
    int ib = idx >> 3;
    int b = ib & (BATCH - 1);
    double ex = Ca[ib] + Cb[ib] - zd[b];
    double scl = exp(ex);
    float4 a = ((const float4*)pa)[idx];
    float4 c = ((const float4*)pb)[idx];
    float4 o;
    o.x = (float)((double)a.x * (double)c.x * scl);
    o.y = (float)((double)a.y * (double)c.y * scl);
    o.z = (float)((double)a.z * (double)c.z * scl);
    o.w = (float)((double)a.w * (double)c.w * scl);
    ((float4*)out)[idx] = o;
}

extern "C" void kernel_launch(void* const* d_in, const int* in_sizes, int n_in,
                              void* d_out, int out_size, void* d_ws, size_t ws_size,
                              hipStream_t stream) {
    const float* features = (const float*)d_in[0];
    const int*   mask     = (const int*)d_in[1];
    const float* W        = (const float*)d_in[2];
    const float* bias     = (const float*)d_in[3];
    const float* trans    = (const float*)d_in[4];
    const float* startp   = (const float*)d_in[5];
    const float* endp     = (const float*)d_in[6];

    char* ws = (char*)d_ws;
    double* Ca = (double*)(ws + 0);
    double* Cb = (double*)(ws + 524288);
    double* zd = (double*)(ws + 1048576);
    float*  Wt = (float*)(ws + 1049600);
    float*  e  = (float*)(ws + 1180672);
    float*  pa = (float*)(ws + 9569280);
    float*  pb = (float*)(ws + 17957888);

    float* probs_out = (float*)d_out;
    float* tags_out  = probs_out + (size_t)SEQ * BATCH * T;

    k_wt<<<128, 256, 0, stream>>>(W, Wt);
    k_emis<<<1024, 256, 0, stream>>>(features, Wt, bias, e);
    k_rec<<<384, 64, 0, stream>>>(e, mask, trans, startp, endp,
                                  pa, pb, Ca, Cb, zd, tags_out);
    k_probs<<<2048, 256, 0, stream>>>(pa, pb, Ca, Cb, zd, probs_out);
}